// Round 1
// baseline (552.219 us; speedup 1.0000x reference)
//
#include <hip/hip_runtime.h>

// ---------------------------------------------------------------- utilities

__global__ __launch_bounds__(256) void k_zero(int* p, int n) {
    int i = blockIdx.x * 256 + threadIdx.x;
    if (i < n) p[i] = 0;
}

__global__ __launch_bounds__(256) void k_hist(const int* __restrict__ dst, int E,
                                              int* __restrict__ counts) {
    int e = blockIdx.x * 256 + threadIdx.x;
    if (e < E) atomicAdd(&counts[dst[e]], 1);
}

__global__ __launch_bounds__(256) void k_dinv(const int* __restrict__ counts,
                                              float* __restrict__ dinv, int n) {
    int i = blockIdx.x * 256 + threadIdx.x;
    if (i < n) dinv[i] = rsqrtf((float)(counts[i] + 1));  // +1 self-loop
}

// exclusive scan over counts -> offs, 3 kernels (n <= 128*1024)
__global__ __launch_bounds__(1024) void k_scan1(const int* __restrict__ counts,
                                                int* __restrict__ offs,
                                                int* __restrict__ partial, int n) {
    __shared__ int sm[1024];
    int t = threadIdx.x;
    int i = blockIdx.x * 1024 + t;
    int v = (i < n) ? counts[i] : 0;
    sm[t] = v;
    __syncthreads();
    for (int d = 1; d < 1024; d <<= 1) {
        int xv = (t >= d) ? sm[t - d] : 0;
        __syncthreads();
        sm[t] += xv;
        __syncthreads();
    }
    if (i < n) offs[i] = sm[t] - v;          // block-local exclusive
    if (t == 1023) partial[blockIdx.x] = sm[1023];
}

__global__ __launch_bounds__(128) void k_scan2(int* partial, int nb) {
    __shared__ int sm[128];
    int t = threadIdx.x;
    int v = (t < nb) ? partial[t] : 0;
    sm[t] = v;
    __syncthreads();
    for (int d = 1; d < 128; d <<= 1) {
        int xv = (t >= d) ? sm[t - d] : 0;
        __syncthreads();
        sm[t] += xv;
        __syncthreads();
    }
    if (t < nb) partial[t] = sm[t] - v;      // exclusive block bases
}

__global__ __launch_bounds__(1024) void k_scan3(const int* __restrict__ partial,
                                                int* __restrict__ offs,
                                                int* __restrict__ cursor, int n, int E) {
    int i = blockIdx.x * 1024 + threadIdx.x;
    if (i < n) {
        int o = offs[i] + partial[blockIdx.x];
        offs[i] = o;
        cursor[i] = o;
    }
    if (i == 0) offs[n] = E;
}

__global__ __launch_bounds__(256) void k_scatter(const int* __restrict__ src,
                                                 const int* __restrict__ dst, int E,
                                                 int* __restrict__ cursor,
                                                 int* __restrict__ csc) {
    int e = blockIdx.x * 256 + threadIdx.x;
    if (e < E) {
        int pos = atomicAdd(&cursor[dst[e]], 1);
        csc[pos] = src[e];
    }
}

// ---------------------------------------------------------------- GEMM
// H[r][c] = (sum_k X[r][k] * W[k][c]) * dinv[r];  K = 128 fixed, BM = 128.
// X tile in LDS as float4[128][32], XOR-swizzled so a-frag (row-stride-8)
// reads hit distinct bank groups. W tile natural [K][BN].
template <int BN>
__global__ __launch_bounds__(256) void gemm_scaled(const float* __restrict__ X,
                                                   const float* __restrict__ W,
                                                   const float* __restrict__ dinv,
                                                   float* __restrict__ H, int nrows) {
    constexpr int BM = 128, K = 128;
    constexpr int TN = BN / 16;  // cols per thread (8 or 4)
    __shared__ float4 xs[BM][K / 4];   // 64 KB
    __shared__ float  wsm[K][BN];      // 64 KB or 32 KB

    const int t = threadIdx.x;
    const int row0 = blockIdx.x * BM;

    // stage W (coalesced float4)
    const float4* W4 = reinterpret_cast<const float4*>(W);
    float4* wsm4 = reinterpret_cast<float4*>(&wsm[0][0]);
#pragma unroll
    for (int i = t; i < K * BN / 4; i += 256) wsm4[i] = W4[i];

    // stage X, swizzled
    const float4* X4 = reinterpret_cast<const float4*>(X);
#pragma unroll
    for (int it = 0; it < 16; ++it) {
        int flat = it * 256 + t;       // 0..4095
        int node = flat >> 5;          // 0..127
        int c4 = flat & 31;            // 0..31
        float4 v = make_float4(0.f, 0.f, 0.f, 0.f);
        int gr = row0 + node;
        if (gr < nrows) v = X4[(size_t)gr * (K / 4) + c4];
        xs[node][c4 ^ ((node >> 3) & 7)] = v;
    }
    __syncthreads();

    const int tx = t & 15;   // col group
    const int ty = t >> 4;   // row group (0..15)

    float acc[8][TN];
#pragma unroll
    for (int i = 0; i < 8; ++i)
#pragma unroll
        for (int j = 0; j < TN; ++j) acc[i][j] = 0.f;

    for (int k4 = 0; k4 < K / 4; ++k4) {
        float4 a[8];
#pragma unroll
        for (int i = 0; i < 8; ++i) a[i] = xs[ty * 8 + i][k4 ^ (ty & 7)];
#pragma unroll
        for (int kk = 0; kk < 4; ++kk) {
            float b[TN];
#pragma unroll
            for (int j = 0; j < TN; ++j) b[j] = wsm[k4 * 4 + kk][tx * TN + j];
#pragma unroll
            for (int i = 0; i < 8; ++i) {
                float av = (&a[i].x)[kk];
#pragma unroll
                for (int j = 0; j < TN; ++j) acc[i][j] = fmaf(av, b[j], acc[i][j]);
            }
        }
    }

#pragma unroll
    for (int i = 0; i < 8; ++i) {
        int r = row0 + ty * 8 + i;
        if (r < nrows) {
            float s = dinv[r];
#pragma unroll
            for (int j = 0; j < TN; ++j) H[(size_t)r * BN + tx * TN + j] = acc[i][j] * s;
        }
    }
}

// ---------------------------------------------------------------- aggregation
// out[i] = act( dinv[i] * (sum_{e in in(i)} h[csc[e]] + h[i]) + bias )
// One wave per node. F=128: float2/lane.  F=64: float/lane.

__global__ __launch_bounds__(256) void k_agg_relu128(const float* __restrict__ h,
                                                     const int* __restrict__ offs,
                                                     const int* __restrict__ csc,
                                                     const float* __restrict__ dinv,
                                                     const float* __restrict__ bias,
                                                     float* __restrict__ out, int n) {
    int node = (blockIdx.x * 256 + threadIdx.x) >> 6;
    int lane = threadIdx.x & 63;
    if (node >= n) return;
    const float2* H2 = reinterpret_cast<const float2*>(h);
    int start = offs[node], end = offs[node + 1];
    float ax = 0.f, ay = 0.f, bx = 0.f, by = 0.f;
    float cx = 0.f, cy = 0.f, dx = 0.f, dy = 0.f;
    int e = start;
    for (; e + 4 <= end; e += 4) {
        int s0 = csc[e], s1 = csc[e + 1], s2 = csc[e + 2], s3 = csc[e + 3];
        float2 v0 = H2[(size_t)s0 * 64 + lane];
        float2 v1 = H2[(size_t)s1 * 64 + lane];
        float2 v2 = H2[(size_t)s2 * 64 + lane];
        float2 v3 = H2[(size_t)s3 * 64 + lane];
        ax += v0.x; ay += v0.y; bx += v1.x; by += v1.y;
        cx += v2.x; cy += v2.y; dx += v3.x; dy += v3.y;
    }
    for (; e < end; ++e) {
        float2 v = H2[(size_t)csc[e] * 64 + lane];
        ax += v.x; ay += v.y;
    }
    float2 vs = H2[(size_t)node * 64 + lane];  // self loop
    float sx = ax + bx + cx + dx + vs.x;
    float sy = ay + by + cy + dy + vs.y;
    float di = dinv[node];
    float2 bb = reinterpret_cast<const float2*>(bias)[lane];
    float ox = fmaxf(fmaf(sx, di, bb.x), 0.f);
    float oy = fmaxf(fmaf(sy, di, bb.y), 0.f);
    reinterpret_cast<float2*>(out)[(size_t)node * 64 + lane] = make_float2(ox, oy);
}

__global__ __launch_bounds__(256) void k_agg_bias64(const float* __restrict__ h,
                                                    const int* __restrict__ offs,
                                                    const int* __restrict__ csc,
                                                    const float* __restrict__ dinv,
                                                    const float* __restrict__ bias,
                                                    float* __restrict__ out, int n) {
    int node = (blockIdx.x * 256 + threadIdx.x) >> 6;
    int lane = threadIdx.x & 63;
    if (node >= n) return;
    int start = offs[node], end = offs[node + 1];
    float a = 0.f, b = 0.f, c = 0.f, d = 0.f;
    int e = start;
    for (; e + 4 <= end; e += 4) {
        int s0 = csc[e], s1 = csc[e + 1], s2 = csc[e + 2], s3 = csc[e + 3];
        a += h[(size_t)s0 * 64 + lane];
        b += h[(size_t)s1 * 64 + lane];
        c += h[(size_t)s2 * 64 + lane];
        d += h[(size_t)s3 * 64 + lane];
    }
    for (; e < end; ++e) a += h[(size_t)csc[e] * 64 + lane];
    float s = a + b + c + d + h[(size_t)node * 64 + lane];
    out[(size_t)node * 64 + lane] = fmaf(s, dinv[node], bias[lane]);
}

// ---------------------------------------------------------------- launch

extern "C" void kernel_launch(void* const* d_in, const int* in_sizes, int n_in,
                              void* d_out, int out_size, void* d_ws, size_t ws_size,
                              hipStream_t stream) {
    const float* x  = (const float*)d_in[0];
    const int*   ei = (const int*)d_in[1];
    const float* W1 = (const float*)d_in[2];
    const float* b1 = (const float*)d_in[3];
    const float* W2 = (const float*)d_in[4];
    const float* b2 = (const float*)d_in[5];
    float* out = (float*)d_out;

    const int n = in_sizes[0] / 128;   // 100000
    const int E = in_sizes[1] / 2;     // 1600000
    const int* src = ei;
    const int* dst = ei + E;

    // workspace carving (256B aligned)
    char* p = (char*)d_ws;
    auto carve = [&](size_t bytes) -> void* {
        void* r = (void*)p;
        p += (bytes + 255) & ~(size_t)255;
        return r;
    };
    int*   counts  = (int*)carve((size_t)n * 4);
    float* dinv    = (float*)carve((size_t)n * 4);
    int*   offs    = (int*)carve((size_t)(n + 1) * 4);
    int*   cursor  = (int*)carve((size_t)n * 4);
    int*   partial = (int*)carve(128 * 4);
    int*   csc     = (int*)carve((size_t)E * 4);
    float* h1      = (float*)carve((size_t)n * 128 * 4);
    float* out1    = (float*)carve((size_t)n * 128 * 4);
    float* h2      = h1;  // h1 dead after layer-1 aggregation; reuse

    const int gn   = (n + 255) / 256;
    const int ge   = (E + 255) / 256;
    const int nb   = (n + 1023) / 1024;  // scan blocks (98)
    const int gemm_blocks = (n + 127) / 128;
    const int gagg = (n + 3) / 4;

    // degree + norm
    k_zero<<<gn, 256, 0, stream>>>(counts, n);
    k_hist<<<ge, 256, 0, stream>>>(dst, E, counts);
    k_dinv<<<gn, 256, 0, stream>>>(counts, dinv, n);

    // CSC build (counting sort by dst)
    k_scan1<<<nb, 1024, 0, stream>>>(counts, offs, partial, n);
    k_scan2<<<1, 128, 0, stream>>>(partial, nb);
    k_scan3<<<nb, 1024, 0, stream>>>(partial, offs, cursor, n, E);
    k_scatter<<<ge, 256, 0, stream>>>(src, dst, E, cursor, csc);

    // layer 1: h1 = (x @ W1) * dinv ; out1 = relu(agg(h1)*dinv + b1)
    gemm_scaled<128><<<gemm_blocks, 256, 0, stream>>>(x, W1, dinv, h1, n);
    k_agg_relu128<<<gagg, 256, 0, stream>>>(h1, offs, csc, dinv, b1, out1, n);

    // layer 2: h2 = (out1 @ W2) * dinv ; out = agg(h2)*dinv + b2
    gemm_scaled<64><<<gemm_blocks, 256, 0, stream>>>(out1, W2, dinv, h2, n);
    k_agg_bias64<<<gagg, 256, 0, stream>>>(h2, offs, csc, dinv, b2, out, n);
}

// Round 2
// 354.168 us; speedup vs baseline: 1.5592x; 1.5592x over previous
//
#include <hip/hip_runtime.h>

// ---------------------------------------------------------------- utilities

__global__ __launch_bounds__(256) void k_zero(int* p, int n) {
    int i = blockIdx.x * 256 + threadIdx.x;
    if (i < n) p[i] = 0;
}

// ------------------------------------------------ bucketed CSC construction
// Bucket = dst >> 8 (256 nodes per bucket). NB = ceil(n/256) <= 512.

__global__ __launch_bounds__(256) void k_bhist(const int* __restrict__ dst, int E,
                                               int* __restrict__ bcnt, int NB, int epb) {
    __shared__ int h[512];
    for (int i = threadIdx.x; i < NB; i += 256) h[i] = 0;
    __syncthreads();
    int lo = blockIdx.x * epb;
    int hi = min(lo + epb, E);
    for (int e = lo + threadIdx.x; e < hi; e += 256)
        atomicAdd(&h[dst[e] >> 8], 1);
    __syncthreads();
    for (int i = threadIdx.x; i < NB; i += 256)
        if (h[i]) atomicAdd(&bcnt[i], h[i]);
}

__global__ __launch_bounds__(512) void k_bscan(const int* __restrict__ bcnt,
                                               int* __restrict__ boffs,
                                               int* __restrict__ bcur, int NB, int E) {
    __shared__ int sm[512];
    int t = threadIdx.x;
    int v = (t < NB) ? bcnt[t] : 0;
    sm[t] = v;
    __syncthreads();
    for (int d = 1; d < 512; d <<= 1) {
        int xv = (t >= d) ? sm[t - d] : 0;
        __syncthreads();
        sm[t] += xv;
        __syncthreads();
    }
    if (t < NB) { boffs[t] = sm[t] - v; bcur[t] = sm[t] - v; }
    if (t == 0) boffs[NB] = E;
}

__global__ __launch_bounds__(256) void k_bscatter(const int* __restrict__ src,
                                                  const int* __restrict__ dst, int E,
                                                  int* __restrict__ bcur,
                                                  int2* __restrict__ pairs, int NB, int epb) {
    __shared__ int h[512];
    __shared__ int base[512];
    for (int i = threadIdx.x; i < NB; i += 256) h[i] = 0;
    __syncthreads();
    int lo = blockIdx.x * epb;
    int hi = min(lo + epb, E);
    for (int e = lo + threadIdx.x; e < hi; e += 256)
        atomicAdd(&h[dst[e] >> 8], 1);
    __syncthreads();
    for (int i = threadIdx.x; i < NB; i += 256) {
        int c = h[i];
        base[i] = c ? atomicAdd(&bcur[i], c) : 0;
        h[i] = 0;  // becomes local cursor
    }
    __syncthreads();
    for (int e = lo + threadIdx.x; e < hi; e += 256) {
        int s = src[e], d = dst[e];
        int b = d >> 8;
        int r = atomicAdd(&h[b], 1);
        pairs[base[b] + r] = make_int2(s, d);
    }
}

// per-bucket exact per-node counts + dinv (replaces global atomic hist)
__global__ __launch_bounds__(256) void k_bcount(const int2* __restrict__ pairs,
                                                const int* __restrict__ boffs,
                                                int* __restrict__ counts,
                                                float* __restrict__ dinv, int n) {
    __shared__ int cnt[256];
    int b = blockIdx.x;
    cnt[threadIdx.x] = 0;
    __syncthreads();
    int lo = boffs[b], hi = boffs[b + 1];
    for (int e = lo + threadIdx.x; e < hi; e += 256)
        atomicAdd(&cnt[pairs[e].y & 255], 1);
    __syncthreads();
    int d = b * 256 + threadIdx.x;
    if (d < n) {
        int c = cnt[threadIdx.x];
        counts[d] = c;
        dinv[d] = rsqrtf((float)(c + 1));  // +1 self-loop
    }
}

// per-bucket final placement: csc positions confined to this bucket's range
__global__ __launch_bounds__(256) void k_bplace(const int2* __restrict__ pairs,
                                                const int* __restrict__ boffs,
                                                const int* __restrict__ offs,
                                                int* __restrict__ csc, int n) {
    __shared__ int cur[256];
    int b = blockIdx.x;
    int d0 = b * 256 + threadIdx.x;
    cur[threadIdx.x] = (d0 < n) ? offs[d0] : 0;
    __syncthreads();
    int lo = boffs[b], hi = boffs[b + 1];
    for (int e = lo + threadIdx.x; e < hi; e += 256) {
        int2 p = pairs[e];
        int pos = atomicAdd(&cur[p.y & 255], 1);
        csc[pos] = p.x;
    }
}

// exclusive scan over counts -> offs, 3 kernels (n <= 128*1024)
__global__ __launch_bounds__(1024) void k_scan1(const int* __restrict__ counts,
                                                int* __restrict__ offs,
                                                int* __restrict__ partial, int n) {
    __shared__ int sm[1024];
    int t = threadIdx.x;
    int i = blockIdx.x * 1024 + t;
    int v = (i < n) ? counts[i] : 0;
    sm[t] = v;
    __syncthreads();
    for (int d = 1; d < 1024; d <<= 1) {
        int xv = (t >= d) ? sm[t - d] : 0;
        __syncthreads();
        sm[t] += xv;
        __syncthreads();
    }
    if (i < n) offs[i] = sm[t] - v;          // block-local exclusive
    if (t == 1023) partial[blockIdx.x] = sm[1023];
}

__global__ __launch_bounds__(128) void k_scan2(int* partial, int nb) {
    __shared__ int sm[128];
    int t = threadIdx.x;
    int v = (t < nb) ? partial[t] : 0;
    sm[t] = v;
    __syncthreads();
    for (int d = 1; d < 128; d <<= 1) {
        int xv = (t >= d) ? sm[t - d] : 0;
        __syncthreads();
        sm[t] += xv;
        __syncthreads();
    }
    if (t < nb) partial[t] = sm[t] - v;      // exclusive block bases
}

__global__ __launch_bounds__(1024) void k_scan3(const int* __restrict__ partial,
                                                int* __restrict__ offs, int n, int E) {
    int i = blockIdx.x * 1024 + threadIdx.x;
    if (i < n) offs[i] += partial[blockIdx.x];
    if (i == 0) offs[n] = E;
}

// ---------------------------------------------------------------- GEMM
// H[r][c] = (sum_k X[r][k] * W[k][c]) * dinv[r];  K = 128 fixed, BM = 128.
// W tile in LDS (64/32 KB -> 2 blocks/CU). A-fragments read from global by
// 16-lane same-address broadcast, register double-buffered across k4 steps.
// Column map per thread: c = tx*4 + 64*j + q -> ds_read_b128 at 64B stride
// (2-way bank alias = free), 256B-contiguous C stores.

__device__ __forceinline__ void load_a8(float4 (&A)[8], const float4* const (&rowp)[8],
                                        int k4) {
#pragma unroll
    for (int i = 0; i < 8; ++i) A[i] = rowp[i][k4];
}

template <int BN4, int TJ>
__device__ __forceinline__ void compute_k4(const float4 (&A)[8],
                                           const float4* __restrict__ ws4,
                                           int k4, int tx, float4 (&acc)[8][TJ]) {
#pragma unroll
    for (int kk = 0; kk < 4; ++kk) {
        const int k = k4 * 4 + kk;
        float4 b[TJ];
#pragma unroll
        for (int j = 0; j < TJ; ++j) b[j] = ws4[k * BN4 + j * 16 + tx];
#pragma unroll
        for (int i = 0; i < 8; ++i) {
            float av = (kk == 0) ? A[i].x : (kk == 1) ? A[i].y
                     : (kk == 2) ? A[i].z : A[i].w;
#pragma unroll
            for (int j = 0; j < TJ; ++j) {
                acc[i][j].x = fmaf(av, b[j].x, acc[i][j].x);
                acc[i][j].y = fmaf(av, b[j].y, acc[i][j].y);
                acc[i][j].z = fmaf(av, b[j].z, acc[i][j].z);
                acc[i][j].w = fmaf(av, b[j].w, acc[i][j].w);
            }
        }
    }
}

template <int BN>
__global__ __launch_bounds__(256) void gemm_scaled(const float* __restrict__ X,
                                                   const float* __restrict__ W,
                                                   const float* __restrict__ dinv,
                                                   float* __restrict__ H, int nrows) {
    constexpr int K = 128, BM = 128;
    constexpr int BN4 = BN / 4;
    constexpr int TJ = BN / 64;               // 2 (BN=128) or 1 (BN=64)
    __shared__ float4 ws4[K * BN4];           // 64 KB or 32 KB

    const int t = threadIdx.x;
    const int tx = t & 15, ty = t >> 4;
    const int row0 = blockIdx.x * BM;

    // stage W (coalesced float4)
    const float4* W4 = reinterpret_cast<const float4*>(W);
    for (int i = t; i < K * BN4; i += 256) ws4[i] = W4[i];

    // clamped row pointers (out-of-range rows read row n-1, results discarded)
    const float4* X4 = reinterpret_cast<const float4*>(X);
    const int rbase = row0 + ty * 8;
    const float4* rowp[8];
#pragma unroll
    for (int i = 0; i < 8; ++i) {
        int r = rbase + i;
        r = (r < nrows) ? r : (nrows - 1);
        rowp[i] = X4 + (size_t)r * (K / 4);
    }

    float4 acc[8][TJ];
#pragma unroll
    for (int i = 0; i < 8; ++i)
#pragma unroll
        for (int j = 0; j < TJ; ++j) acc[i][j] = make_float4(0.f, 0.f, 0.f, 0.f);

    float4 aA[8], aB[8];
    load_a8(aA, rowp, 0);
    __syncthreads();  // W staged

    for (int k4 = 0; k4 < 32; k4 += 2) {
        load_a8(aB, rowp, k4 + 1);
        compute_k4<BN4, TJ>(aA, ws4, k4, tx, acc);
        if (k4 + 2 < 32) load_a8(aA, rowp, k4 + 2);
        compute_k4<BN4, TJ>(aB, ws4, k4 + 1, tx, acc);
    }

    float4* H4 = reinterpret_cast<float4*>(H);
#pragma unroll
    for (int i = 0; i < 8; ++i) {
        int r = rbase + i;
        if (r < nrows) {
            float s = dinv[r];
#pragma unroll
            for (int j = 0; j < TJ; ++j) {
                float4 v = acc[i][j];
                v.x *= s; v.y *= s; v.z *= s; v.w *= s;
                H4[(size_t)r * BN4 + j * 16 + tx] = v;
            }
        }
    }
}

// ---------------------------------------------------------------- aggregation
// out[i] = act( dinv[i] * (sum_{e in in(i)} h[csc[e]] + h[i]) + bias )
// One wave per node. F=128: float2/lane.  F=64: float/lane.

__global__ __launch_bounds__(256) void k_agg_relu128(const float* __restrict__ h,
                                                     const int* __restrict__ offs,
                                                     const int* __restrict__ csc,
                                                     const float* __restrict__ dinv,
                                                     const float* __restrict__ bias,
                                                     float* __restrict__ out, int n) {
    int node = (blockIdx.x * 256 + threadIdx.x) >> 6;
    int lane = threadIdx.x & 63;
    if (node >= n) return;
    const float2* H2 = reinterpret_cast<const float2*>(h);
    int start = offs[node], end = offs[node + 1];
    float ax = 0.f, ay = 0.f, bx = 0.f, by = 0.f;
    float cx = 0.f, cy = 0.f, dx = 0.f, dy = 0.f;
    int e = start;
    for (; e + 4 <= end; e += 4) {
        int s0 = csc[e], s1 = csc[e + 1], s2 = csc[e + 2], s3 = csc[e + 3];
        float2 v0 = H2[(size_t)s0 * 64 + lane];
        float2 v1 = H2[(size_t)s1 * 64 + lane];
        float2 v2 = H2[(size_t)s2 * 64 + lane];
        float2 v3 = H2[(size_t)s3 * 64 + lane];
        ax += v0.x; ay += v0.y; bx += v1.x; by += v1.y;
        cx += v2.x; cy += v2.y; dx += v3.x; dy += v3.y;
    }
    for (; e < end; ++e) {
        float2 v = H2[(size_t)csc[e] * 64 + lane];
        ax += v.x; ay += v.y;
    }
    float2 vs = H2[(size_t)node * 64 + lane];  // self loop
    float sx = ax + bx + cx + dx + vs.x;
    float sy = ay + by + cy + dy + vs.y;
    float di = dinv[node];
    float2 bb = reinterpret_cast<const float2*>(bias)[lane];
    float ox = fmaxf(fmaf(sx, di, bb.x), 0.f);
    float oy = fmaxf(fmaf(sy, di, bb.y), 0.f);
    reinterpret_cast<float2*>(out)[(size_t)node * 64 + lane] = make_float2(ox, oy);
}

__global__ __launch_bounds__(256) void k_agg_bias64(const float* __restrict__ h,
                                                    const int* __restrict__ offs,
                                                    const int* __restrict__ csc,
                                                    const float* __restrict__ dinv,
                                                    const float* __restrict__ bias,
                                                    float* __restrict__ out, int n) {
    int node = (blockIdx.x * 256 + threadIdx.x) >> 6;
    int lane = threadIdx.x & 63;
    if (node >= n) return;
    int start = offs[node], end = offs[node + 1];
    float a = 0.f, b = 0.f, c = 0.f, d = 0.f;
    int e = start;
    for (; e + 4 <= end; e += 4) {
        int s0 = csc[e], s1 = csc[e + 1], s2 = csc[e + 2], s3 = csc[e + 3];
        a += h[(size_t)s0 * 64 + lane];
        b += h[(size_t)s1 * 64 + lane];
        c += h[(size_t)s2 * 64 + lane];
        d += h[(size_t)s3 * 64 + lane];
    }
    for (; e < end; ++e) a += h[(size_t)csc[e] * 64 + lane];
    float s = a + b + c + d + h[(size_t)node * 64 + lane];
    out[(size_t)node * 64 + lane] = fmaf(s, dinv[node], bias[lane]);
}

// ---------------------------------------------------------------- launch

extern "C" void kernel_launch(void* const* d_in, const int* in_sizes, int n_in,
                              void* d_out, int out_size, void* d_ws, size_t ws_size,
                              hipStream_t stream) {
    const float* x  = (const float*)d_in[0];
    const int*   ei = (const int*)d_in[1];
    const float* W1 = (const float*)d_in[2];
    const float* b1 = (const float*)d_in[3];
    const float* W2 = (const float*)d_in[4];
    const float* b2 = (const float*)d_in[5];
    float* out = (float*)d_out;

    const int n = in_sizes[0] / 128;   // 100000
    const int E = in_sizes[1] / 2;     // 1600000
    const int* src = ei;
    const int* dst = ei + E;
    const int NB = (n + 255) / 256;    // 391 buckets of 256 nodes

    // workspace carving (256B aligned)
    char* p = (char*)d_ws;
    auto carve = [&](size_t bytes) -> void* {
        void* r = (void*)p;
        p += (bytes + 255) & ~(size_t)255;
        return r;
    };
    int*   counts  = (int*)carve((size_t)n * 4);
    float* dinv    = (float*)carve((size_t)n * 4);
    int*   offs    = (int*)carve((size_t)(n + 1) * 4);
    int*   partial = (int*)carve(128 * 4);
    int*   bcnt    = (int*)carve((size_t)(NB + 1) * 4);
    int*   boffs   = (int*)carve((size_t)(NB + 1) * 4);
    int*   bcur    = (int*)carve((size_t)(NB + 1) * 4);
    int*   csc     = (int*)carve((size_t)E * 4);
    float* h1      = (float*)carve((size_t)n * 128 * 4);
    float* out1    = (float*)carve((size_t)n * 128 * 4);
    int2*  pairs   = (int2*)h1;  // pairs dead before gemm1 writes h1
    float* h2      = h1;         // h1 dead after layer-1 aggregation

    const int nb   = (n + 1023) / 1024;  // scan blocks (98 <= 128)
    const int gemm_blocks = (n + 127) / 128;
    const int gagg = (n + 3) / 4;
    const int GB   = 256;                // bucket-pass blocks
    const int epb  = (E + GB - 1) / GB;  // edges per block

    // ---- CSC build (bucketed counting sort by dst) ----
    k_zero<<<(NB + 256) / 256, 256, 0, stream>>>(bcnt, NB + 1);
    k_bhist<<<GB, 256, 0, stream>>>(dst, E, bcnt, NB, epb);
    k_bscan<<<1, 512, 0, stream>>>(bcnt, boffs, bcur, NB, E);
    k_bscatter<<<GB, 256, 0, stream>>>(src, dst, E, bcur, pairs, NB, epb);
    k_bcount<<<NB, 256, 0, stream>>>(pairs, boffs, counts, dinv, n);
    k_scan1<<<nb, 1024, 0, stream>>>(counts, offs, partial, n);
    k_scan2<<<1, 128, 0, stream>>>(partial, nb);
    k_scan3<<<nb, 1024, 0, stream>>>(partial, offs, n, E);
    k_bplace<<<NB, 256, 0, stream>>>(pairs, boffs, offs, csc, n);

    // ---- layer 1: h1 = (x @ W1) * dinv ; out1 = relu(agg(h1)*dinv + b1) ----
    gemm_scaled<128><<<gemm_blocks, 256, 0, stream>>>(x, W1, dinv, h1, n);
    k_agg_relu128<<<gagg, 256, 0, stream>>>(h1, offs, csc, dinv, b1, out1, n);

    // ---- layer 2: h2 = (out1 @ W2) * dinv ; out = agg(h2)*dinv + b2 ----
    gemm_scaled<64><<<gemm_blocks, 256, 0, stream>>>(out1, W2, dinv, h2, n);
    k_agg_bias64<<<gagg, 256, 0, stream>>>(h2, offs, csc, dinv, b2, out, n);
}

// Round 3
// 298.907 us; speedup vs baseline: 1.8475x; 1.1849x over previous
//
#include <hip/hip_runtime.h>
#include <hip/hip_fp16.h>

// ---------------------------------------------------------------- helpers

__device__ __forceinline__ unsigned pack_half2(float x, float y) {
    __half2 h = __float22half2_rn(make_float2(x, y));
    return *reinterpret_cast<unsigned*>(&h);
}

// ---------------------------------------------------------------- utilities

__global__ __launch_bounds__(256) void k_zero(int* p, int n) {
    int i = blockIdx.x * 256 + threadIdx.x;
    if (i < n) p[i] = 0;
}

// ------------------------------------------------ bucketed CSC construction
// Bucket = dst >> 8 (256 nodes per bucket). NB = ceil(n/256) <= 512.

__global__ __launch_bounds__(256) void k_bhist(const int* __restrict__ dst, int E,
                                               int* __restrict__ bcnt, int NB, int epb) {
    __shared__ int h[512];
    for (int i = threadIdx.x; i < NB; i += 256) h[i] = 0;
    __syncthreads();
    int lo = blockIdx.x * epb;
    int hi = min(lo + epb, E);
    for (int e = lo + threadIdx.x; e < hi; e += 256)
        atomicAdd(&h[dst[e] >> 8], 1);
    __syncthreads();
    for (int i = threadIdx.x; i < NB; i += 256)
        if (h[i]) atomicAdd(&bcnt[i], h[i]);
}

__global__ __launch_bounds__(512) void k_bscan(const int* __restrict__ bcnt,
                                               int* __restrict__ boffs,
                                               int* __restrict__ bcur, int NB, int E) {
    __shared__ int sm[512];
    int t = threadIdx.x;
    int v = (t < NB) ? bcnt[t] : 0;
    sm[t] = v;
    __syncthreads();
    for (int d = 1; d < 512; d <<= 1) {
        int xv = (t >= d) ? sm[t - d] : 0;
        __syncthreads();
        sm[t] += xv;
        __syncthreads();
    }
    if (t < NB) { boffs[t] = sm[t] - v; bcur[t] = sm[t] - v; }
    if (t == 0) boffs[NB] = E;
}

__global__ __launch_bounds__(256) void k_bscatter(const int* __restrict__ src,
                                                  const int* __restrict__ dst, int E,
                                                  int* __restrict__ bcur,
                                                  int2* __restrict__ pairs, int NB, int epb) {
    __shared__ int h[512];
    __shared__ int base[512];
    for (int i = threadIdx.x; i < NB; i += 256) h[i] = 0;
    __syncthreads();
    int lo = blockIdx.x * epb;
    int hi = min(lo + epb, E);
    for (int e = lo + threadIdx.x; e < hi; e += 256)
        atomicAdd(&h[dst[e] >> 8], 1);
    __syncthreads();
    for (int i = threadIdx.x; i < NB; i += 256) {
        int c = h[i];
        base[i] = c ? atomicAdd(&bcur[i], c) : 0;
        h[i] = 0;  // becomes local cursor
    }
    __syncthreads();
    for (int e = lo + threadIdx.x; e < hi; e += 256) {
        int s = src[e], d = dst[e];
        int b = d >> 8;
        int r = atomicAdd(&h[b], 1);
        pairs[base[b] + r] = make_int2(s, d);
    }
}

// per-bucket: exact per-node counts -> dinv, LDS exclusive scan -> offs
__global__ __launch_bounds__(256) void k_bcount_scan(const int2* __restrict__ pairs,
                                                     const int* __restrict__ boffs,
                                                     float* __restrict__ dinv,
                                                     int* __restrict__ offs,
                                                     int n, int E, int NB) {
    __shared__ int cnt[256];
    __shared__ int scn[256];
    int b = blockIdx.x, t = threadIdx.x;
    cnt[t] = 0;
    __syncthreads();
    int lo = boffs[b], hi = boffs[b + 1];
    for (int e = lo + t; e < hi; e += 256)
        atomicAdd(&cnt[pairs[e].y & 255], 1);
    __syncthreads();
    int c = cnt[t];
    int node = b * 256 + t;
    if (node < n) dinv[node] = rsqrtf((float)(c + 1));  // +1 self-loop
    scn[t] = c;
    __syncthreads();
    for (int d = 1; d < 256; d <<= 1) {
        int xv = (t >= d) ? scn[t - d] : 0;
        __syncthreads();
        scn[t] += xv;
        __syncthreads();
    }
    if (node < n) offs[node] = boffs[b] + scn[t] - c;
    if (b == NB - 1 && t == 255) offs[n] = E;
}

// per-bucket final placement: csc positions confined to this bucket's range
__global__ __launch_bounds__(256) void k_bplace(const int2* __restrict__ pairs,
                                                const int* __restrict__ boffs,
                                                const int* __restrict__ offs,
                                                int* __restrict__ csc, int n) {
    __shared__ int cur[256];
    int b = blockIdx.x;
    int d0 = b * 256 + threadIdx.x;
    cur[threadIdx.x] = (d0 < n) ? offs[d0] : 0;
    __syncthreads();
    int lo = boffs[b], hi = boffs[b + 1];
    for (int e = lo + threadIdx.x; e < hi; e += 256) {
        int2 p = pairs[e];
        int pos = atomicAdd(&cur[p.y & 255], 1);
        csc[pos] = p.x;
    }
}

// ---------------------------------------------------------------- GEMM 1
// H[r][c] = (sum_k X[r][k] * W[k][c]) * dinv[r], fp32 in, FP16 out.
// K = 128, BM = 128, BN = 128. W in LDS (64 KB). A via 16-lane broadcast
// from global, register double-buffered. c = tx*4 + 64*j.

__device__ __forceinline__ void load_a8(float4 (&A)[8], const float4* const (&rowp)[8],
                                        int k4) {
#pragma unroll
    for (int i = 0; i < 8; ++i) A[i] = rowp[i][k4];
}

template <int BN4, int TJ>
__device__ __forceinline__ void compute_k4(const float4 (&A)[8],
                                           const float4* __restrict__ ws4,
                                           int k4, int tx, float4 (&acc)[8][TJ]) {
#pragma unroll
    for (int kk = 0; kk < 4; ++kk) {
        const int k = k4 * 4 + kk;
        float4 b[TJ];
#pragma unroll
        for (int j = 0; j < TJ; ++j) b[j] = ws4[k * BN4 + j * 16 + tx];
#pragma unroll
        for (int i = 0; i < 8; ++i) {
            float av = (kk == 0) ? A[i].x : (kk == 1) ? A[i].y
                     : (kk == 2) ? A[i].z : A[i].w;
#pragma unroll
            for (int j = 0; j < TJ; ++j) {
                acc[i][j].x = fmaf(av, b[j].x, acc[i][j].x);
                acc[i][j].y = fmaf(av, b[j].y, acc[i][j].y);
                acc[i][j].z = fmaf(av, b[j].z, acc[i][j].z);
                acc[i][j].w = fmaf(av, b[j].w, acc[i][j].w);
            }
        }
    }
}

__global__ __launch_bounds__(256) void gemm1_f32_h16(const float* __restrict__ X,
                                                     const float* __restrict__ W,
                                                     const float* __restrict__ dinv,
                                                     __half* __restrict__ H, int nrows) {
    constexpr int K = 128, BM = 128, BN = 128;
    constexpr int BN4 = BN / 4, TJ = 2;
    __shared__ float4 ws4[K * BN4];  // 64 KB

    const int t = threadIdx.x;
    const int tx = t & 15, ty = t >> 4;
    const int row0 = blockIdx.x * BM;

    const float4* W4 = reinterpret_cast<const float4*>(W);
    for (int i = t; i < K * BN4; i += 256) ws4[i] = W4[i];

    const float4* X4 = reinterpret_cast<const float4*>(X);
    const int rbase = row0 + ty * 8;
    const float4* rowp[8];
#pragma unroll
    for (int i = 0; i < 8; ++i) {
        int r = rbase + i;
        r = (r < nrows) ? r : (nrows - 1);
        rowp[i] = X4 + (size_t)r * (K / 4);
    }

    float4 acc[8][TJ];
#pragma unroll
    for (int i = 0; i < 8; ++i)
#pragma unroll
        for (int j = 0; j < TJ; ++j) acc[i][j] = make_float4(0.f, 0.f, 0.f, 0.f);

    float4 aA[8], aB[8];
    load_a8(aA, rowp, 0);
    __syncthreads();

    for (int k4 = 0; k4 < 32; k4 += 2) {
        load_a8(aB, rowp, k4 + 1);
        compute_k4<BN4, TJ>(aA, ws4, k4, tx, acc);
        if (k4 + 2 < 32) load_a8(aA, rowp, k4 + 2);
        compute_k4<BN4, TJ>(aB, ws4, k4 + 1, tx, acc);
    }

    uint2* H8 = reinterpret_cast<uint2*>(H);  // 8B = 4 halfs; row = 32 uint2
#pragma unroll
    for (int i = 0; i < 8; ++i) {
        int r = rbase + i;
        if (r < nrows) {
            float s = dinv[r];
#pragma unroll
            for (int j = 0; j < TJ; ++j) {
                float4 v = acc[i][j];
                H8[(size_t)r * 32 + j * 16 + tx] =
                    make_uint2(pack_half2(v.x * s, v.y * s), pack_half2(v.z * s, v.w * s));
            }
        }
    }
}

// ---------------------------------------------------------------- GEMM 2
// fp16 in (out1), fp16 out (h2). K = 128, BM = 128, BN = 64. W2 LDS 32 KB.

__global__ __launch_bounds__(256) void gemm2_h16_h16(const __half* __restrict__ Xh,
                                                     const float* __restrict__ W,
                                                     const float* __restrict__ dinv,
                                                     __half* __restrict__ H, int nrows) {
    constexpr int K = 128, BM = 128, BN = 64;
    constexpr int BN4 = BN / 4;               // 16
    __shared__ float4 ws4[K * BN4];           // 32 KB

    const int t = threadIdx.x;
    const int tx = t & 15, ty = t >> 4;
    const int row0 = blockIdx.x * BM;

    const float4* W4 = reinterpret_cast<const float4*>(W);
    for (int i = t; i < K * BN4; i += 256) ws4[i] = W4[i];

    // fp16 rows: 256 B = 16 float4 chunks of 8 halfs each
    const float4* X4 = reinterpret_cast<const float4*>(Xh);
    const int rbase = row0 + ty * 8;
    const float4* rowp[8];
#pragma unroll
    for (int i = 0; i < 8; ++i) {
        int r = rbase + i;
        r = (r < nrows) ? r : (nrows - 1);
        rowp[i] = X4 + (size_t)r * (K / 8);
    }

    float4 acc[8];
#pragma unroll
    for (int i = 0; i < 8; ++i) acc[i] = make_float4(0.f, 0.f, 0.f, 0.f);

    float4 aA[8], aB[8];
    load_a8(aA, rowp, 0);
    __syncthreads();

    auto compute_k8 = [&](const float4(&A)[8], int c8) {
#pragma unroll
        for (int kk = 0; kk < 8; ++kk) {
            const int k = c8 * 8 + kk;
            float4 b = ws4[k * BN4 + tx];
#pragma unroll
            for (int i = 0; i < 8; ++i) {
                const __half2* hp = reinterpret_cast<const __half2*>(&A[i]);
                __half2 pr = hp[kk >> 1];
                float av = (kk & 1) ? __high2float(pr) : __low2float(pr);
                acc[i].x = fmaf(av, b.x, acc[i].x);
                acc[i].y = fmaf(av, b.y, acc[i].y);
                acc[i].z = fmaf(av, b.z, acc[i].z);
                acc[i].w = fmaf(av, b.w, acc[i].w);
            }
        }
    };

    for (int c8 = 0; c8 < 16; c8 += 2) {
        load_a8(aB, rowp, c8 + 1);
        compute_k8(aA, c8);
        if (c8 + 2 < 16) load_a8(aA, rowp, c8 + 2);
        compute_k8(aB, c8 + 1);
    }

    uint2* H8 = reinterpret_cast<uint2*>(H);  // row = 64 halfs = 16 uint2
#pragma unroll
    for (int i = 0; i < 8; ++i) {
        int r = rbase + i;
        if (r < nrows) {
            float s = dinv[r];
            float4 v = acc[i];
            H8[(size_t)r * 16 + tx] =
                make_uint2(pack_half2(v.x * s, v.y * s), pack_half2(v.z * s, v.w * s));
        }
    }
}

// ---------------------------------------------------------------- aggregation
// out[i] = act( dinv[i] * (sum_{e in in(i)} h[csc[e]] + h[i]) + bias )
// One wave per node, fp16 gathers, fp32 accumulate.

__global__ __launch_bounds__(256) void k_agg_relu128h(const __half* __restrict__ h,
                                                      const int* __restrict__ offs,
                                                      const int* __restrict__ csc,
                                                      const float* __restrict__ dinv,
                                                      const float* __restrict__ bias,
                                                      __half* __restrict__ out, int n) {
    int node = (blockIdx.x * 256 + threadIdx.x) >> 6;
    int lane = threadIdx.x & 63;
    if (node >= n) return;
    const __half2* H2 = reinterpret_cast<const __half2*>(h);  // row = 64 half2
    int start = offs[node], end = offs[node + 1];
    float ax = 0.f, ay = 0.f, bx = 0.f, by = 0.f;
    float cx = 0.f, cy = 0.f, dx = 0.f, dy = 0.f;
    int e = start;
    for (; e + 4 <= end; e += 4) {
        int s0 = csc[e], s1 = csc[e + 1], s2 = csc[e + 2], s3 = csc[e + 3];
        float2 v0 = __half22float2(H2[(size_t)s0 * 64 + lane]);
        float2 v1 = __half22float2(H2[(size_t)s1 * 64 + lane]);
        float2 v2 = __half22float2(H2[(size_t)s2 * 64 + lane]);
        float2 v3 = __half22float2(H2[(size_t)s3 * 64 + lane]);
        ax += v0.x; ay += v0.y; bx += v1.x; by += v1.y;
        cx += v2.x; cy += v2.y; dx += v3.x; dy += v3.y;
    }
    for (; e < end; ++e) {
        float2 v = __half22float2(H2[(size_t)csc[e] * 64 + lane]);
        ax += v.x; ay += v.y;
    }
    float2 vs = __half22float2(H2[(size_t)node * 64 + lane]);  // self loop
    float sx = ax + bx + cx + dx + vs.x;
    float sy = ay + by + cy + dy + vs.y;
    float di = dinv[node];
    float2 bb = reinterpret_cast<const float2*>(bias)[lane];
    float ox = fmaxf(fmaf(sx, di, bb.x), 0.f);
    float oy = fmaxf(fmaf(sy, di, bb.y), 0.f);
    reinterpret_cast<unsigned*>(out)[(size_t)node * 64 + lane] = pack_half2(ox, oy);
}

__global__ __launch_bounds__(256) void k_agg_bias64h(const __half* __restrict__ h,
                                                     const int* __restrict__ offs,
                                                     const int* __restrict__ csc,
                                                     const float* __restrict__ dinv,
                                                     const float* __restrict__ bias,
                                                     float* __restrict__ out, int n) {
    int node = (blockIdx.x * 256 + threadIdx.x) >> 6;
    int lane = threadIdx.x & 63;
    if (node >= n) return;
    int start = offs[node], end = offs[node + 1];
    float a = 0.f, b = 0.f, c = 0.f, d = 0.f;
    int e = start;
    for (; e + 4 <= end; e += 4) {
        int s0 = csc[e], s1 = csc[e + 1], s2 = csc[e + 2], s3 = csc[e + 3];
        a += __half2float(h[(size_t)s0 * 64 + lane]);
        b += __half2float(h[(size_t)s1 * 64 + lane]);
        c += __half2float(h[(size_t)s2 * 64 + lane]);
        d += __half2float(h[(size_t)s3 * 64 + lane]);
    }
    for (; e < end; ++e) a += __half2float(h[(size_t)csc[e] * 64 + lane]);
    float s = a + b + c + d + __half2float(h[(size_t)node * 64 + lane]);
    out[(size_t)node * 64 + lane] = fmaf(s, dinv[node], bias[lane]);
}

// ---------------------------------------------------------------- launch

extern "C" void kernel_launch(void* const* d_in, const int* in_sizes, int n_in,
                              void* d_out, int out_size, void* d_ws, size_t ws_size,
                              hipStream_t stream) {
    const float* x  = (const float*)d_in[0];
    const int*   ei = (const int*)d_in[1];
    const float* W1 = (const float*)d_in[2];
    const float* b1 = (const float*)d_in[3];
    const float* W2 = (const float*)d_in[4];
    const float* b2 = (const float*)d_in[5];
    float* out = (float*)d_out;

    const int n = in_sizes[0] / 128;   // 100000
    const int E = in_sizes[1] / 2;     // 1600000
    const int* src = ei;
    const int* dst = ei + E;
    const int NB = (n + 255) / 256;    // 391 buckets of 256 nodes

    // workspace carving (256B aligned)
    char* p = (char*)d_ws;
    auto carve = [&](size_t bytes) -> void* {
        void* r = (void*)p;
        p += (bytes + 255) & ~(size_t)255;
        return r;
    };
    float* dinv    = (float*)carve((size_t)n * 4);
    int*   offs    = (int*)carve((size_t)(n + 1) * 4);
    int*   bcnt    = (int*)carve((size_t)(NB + 1) * 4);
    int*   boffs   = (int*)carve((size_t)(NB + 1) * 4);
    int*   bcur    = (int*)carve((size_t)(NB + 1) * 4);
    int*   csc     = (int*)carve((size_t)E * 4);
    __half* h1     = (__half*)carve((size_t)n * 128 * 2);   // 25.6 MB
    __half* out1   = (__half*)carve((size_t)n * 128 * 2);   // 25.6 MB
    int2*  pairs   = (int2*)h1;   // E*8 = 12.8 MB <= 25.6 MB; dead before gemm1
    __half* h2     = h1;          // h1 dead after layer-1 aggregation

    const int gemm_blocks = (n + 127) / 128;
    const int gagg = (n + 3) / 4;
    const int GB   = 256;                // bucket-pass blocks
    const int epb  = (E + GB - 1) / GB;  // edges per block

    // ---- CSC build (bucketed counting sort by dst) ----
    k_zero<<<(NB + 256) / 256, 256, 0, stream>>>(bcnt, NB + 1);
    k_bhist<<<GB, 256, 0, stream>>>(dst, E, bcnt, NB, epb);
    k_bscan<<<1, 512, 0, stream>>>(bcnt, boffs, bcur, NB, E);
    k_bscatter<<<GB, 256, 0, stream>>>(src, dst, E, bcur, pairs, NB, epb);
    k_bcount_scan<<<NB, 256, 0, stream>>>(pairs, boffs, dinv, offs, n, E, NB);
    k_bplace<<<NB, 256, 0, stream>>>(pairs, boffs, offs, csc, n);

    // ---- layer 1: h1 = (x @ W1) * dinv ; out1 = relu(agg(h1)*dinv + b1) ----
    gemm1_f32_h16<<<gemm_blocks, 256, 0, stream>>>(x, W1, dinv, h1, n);
    k_agg_relu128h<<<gagg, 256, 0, stream>>>(h1, offs, csc, dinv, b1, out1, n);

    // ---- layer 2: h2 = (out1 @ W2) * dinv ; out = agg(h2)*dinv + b2 ----
    gemm2_h16_h16<<<gemm_blocks, 256, 0, stream>>>(out1, W2, dinv, h2, n);
    k_agg_bias64h<<<gagg, 256, 0, stream>>>(h2, offs, csc, dinv, b2, out, n);
}

// Round 4
// 262.726 us; speedup vs baseline: 2.1019x; 1.1377x over previous
//
#include <hip/hip_runtime.h>
#include <hip/hip_fp16.h>

// ---------------------------------------------------------------- helpers

__device__ __forceinline__ unsigned pack_half2(float x, float y) {
    __half2 h = __float22half2_rn(make_float2(x, y));
    return *reinterpret_cast<unsigned*>(&h);
}
__device__ __forceinline__ float2 up2(unsigned u) {
    __half2 h = *reinterpret_cast<__half2*>(&u);
    return __half22float2(h);
}
__device__ __forceinline__ void acc8(float4& a, uint2 v) {
    float2 p = up2(v.x), q = up2(v.y);
    a.x += p.x; a.y += p.y; a.z += q.x; a.w += q.y;
}
__device__ __forceinline__ void acc4(float2& a, unsigned v) {
    float2 p = up2(v);
    a.x += p.x; a.y += p.y;
}

// ---------------------------------------------------------------- utilities

__global__ __launch_bounds__(256) void k_zero(int* p, int n) {
    int i = blockIdx.x * 256 + threadIdx.x;
    if (i < n) p[i] = 0;
}

// ------------------------------------------------ bucketed CSC construction
// Bucket = dst >> 8 (256 nodes). NB <= 512. Pair packed: src(24b) | dstLow8(8b).

__global__ __launch_bounds__(256) void k_bhist(const int* __restrict__ dst, int E,
                                               int* __restrict__ bcnt, int NB, int epb) {
    __shared__ int h[512];
    for (int i = threadIdx.x; i < NB; i += 256) h[i] = 0;
    __syncthreads();
    int lo = blockIdx.x * epb;
    int hi = min(lo + epb, E);
    for (int e = lo + threadIdx.x; e < hi; e += 256)
        atomicAdd(&h[dst[e] >> 8], 1);
    __syncthreads();
    for (int i = threadIdx.x; i < NB; i += 256)
        if (h[i]) atomicAdd(&bcnt[i], h[i]);
}

__global__ __launch_bounds__(512) void k_bscan(const int* __restrict__ bcnt,
                                               int* __restrict__ boffs,
                                               int* __restrict__ bcur, int NB, int E) {
    __shared__ int sm[512];
    int t = threadIdx.x;
    int v = (t < NB) ? bcnt[t] : 0;
    sm[t] = v;
    __syncthreads();
    for (int d = 1; d < 512; d <<= 1) {
        int xv = (t >= d) ? sm[t - d] : 0;
        __syncthreads();
        sm[t] += xv;
        __syncthreads();
    }
    if (t < NB) { boffs[t] = sm[t] - v; bcur[t] = sm[t] - v; }
    if (t == 0) boffs[NB] = E;
}

__global__ __launch_bounds__(256) void k_bscatter(const int* __restrict__ src,
                                                  const int* __restrict__ dst, int E,
                                                  int* __restrict__ bcur,
                                                  unsigned* __restrict__ pairs,
                                                  int NB, int epb) {
    __shared__ int h[512];
    __shared__ int base[512];
    for (int i = threadIdx.x; i < NB; i += 256) h[i] = 0;
    __syncthreads();
    int lo = blockIdx.x * epb;
    int hi = min(lo + epb, E);
    for (int e = lo + threadIdx.x; e < hi; e += 256)
        atomicAdd(&h[dst[e] >> 8], 1);
    __syncthreads();
    for (int i = threadIdx.x; i < NB; i += 256) {
        int c = h[i];
        base[i] = c ? atomicAdd(&bcur[i], c) : 0;
        h[i] = 0;  // becomes local cursor
    }
    __syncthreads();
    for (int e = lo + threadIdx.x; e < hi; e += 256) {
        int s = src[e], d = dst[e];
        int b = d >> 8;
        int r = atomicAdd(&h[b], 1);
        pairs[base[b] + r] = (unsigned)s | ((unsigned)(d & 255) << 24);
    }
}

// per-bucket: counts -> dinv, LDS exclusive scan -> offs, then csc placement
__global__ __launch_bounds__(256) void k_bfinal(const unsigned* __restrict__ pairs,
                                                const int* __restrict__ boffs,
                                                float* __restrict__ dinv,
                                                int* __restrict__ offs,
                                                int* __restrict__ csc,
                                                int n, int E, int NB) {
    __shared__ int cnt[256];
    __shared__ int scn[256];
    int b = blockIdx.x, t = threadIdx.x;
    cnt[t] = 0;
    __syncthreads();
    int lo = boffs[b], hi = boffs[b + 1];
    for (int e = lo + t; e < hi; e += 256)
        atomicAdd(&cnt[pairs[e] >> 24], 1);
    __syncthreads();
    int c = cnt[t];
    int node = b * 256 + t;
    if (node < n) dinv[node] = rsqrtf((float)(c + 1));  // +1 self-loop
    scn[t] = c;
    __syncthreads();
    for (int d = 1; d < 256; d <<= 1) {
        int xv = (t >= d) ? scn[t - d] : 0;
        __syncthreads();
        scn[t] += xv;
        __syncthreads();
    }
    int myoff = lo + scn[t] - c;
    if (node < n) offs[node] = myoff;
    if (b == NB - 1 && t == 255) offs[n] = E;
    cnt[t] = myoff;  // reuse as absolute cursor
    __syncthreads();
    for (int e = lo + t; e < hi; e += 256) {
        unsigned p = pairs[e];
        int pos = atomicAdd(&cnt[p >> 24], 1);
        csc[pos] = (int)(p & 0x00FFFFFFu);
    }
}

// ---------------------------------------------------------------- GEMM 1
// H[r][c] = (sum_k X[r][k] * W[k][c]) * dinv[r], fp32 in, FP16 out.

__device__ __forceinline__ void load_a8(float4 (&A)[8], const float4* const (&rowp)[8],
                                        int k4) {
#pragma unroll
    for (int i = 0; i < 8; ++i) A[i] = rowp[i][k4];
}

template <int BN4, int TJ>
__device__ __forceinline__ void compute_k4(const float4 (&A)[8],
                                           const float4* __restrict__ ws4,
                                           int k4, int tx, float4 (&acc)[8][TJ]) {
#pragma unroll
    for (int kk = 0; kk < 4; ++kk) {
        const int k = k4 * 4 + kk;
        float4 b[TJ];
#pragma unroll
        for (int j = 0; j < TJ; ++j) b[j] = ws4[k * BN4 + j * 16 + tx];
#pragma unroll
        for (int i = 0; i < 8; ++i) {
            float av = (kk == 0) ? A[i].x : (kk == 1) ? A[i].y
                     : (kk == 2) ? A[i].z : A[i].w;
#pragma unroll
            for (int j = 0; j < TJ; ++j) {
                acc[i][j].x = fmaf(av, b[j].x, acc[i][j].x);
                acc[i][j].y = fmaf(av, b[j].y, acc[i][j].y);
                acc[i][j].z = fmaf(av, b[j].z, acc[i][j].z);
                acc[i][j].w = fmaf(av, b[j].w, acc[i][j].w);
            }
        }
    }
}

__global__ __launch_bounds__(256) void gemm1_f32_h16(const float* __restrict__ X,
                                                     const float* __restrict__ W,
                                                     const float* __restrict__ dinv,
                                                     __half* __restrict__ H, int nrows) {
    constexpr int K = 128, BM = 128, BN = 128;
    constexpr int BN4 = BN / 4, TJ = 2;
    __shared__ float4 ws4[K * BN4];  // 64 KB

    const int t = threadIdx.x;
    const int tx = t & 15, ty = t >> 4;
    const int row0 = blockIdx.x * BM;

    const float4* W4 = reinterpret_cast<const float4*>(W);
    for (int i = t; i < K * BN4; i += 256) ws4[i] = W4[i];

    const float4* X4 = reinterpret_cast<const float4*>(X);
    const int rbase = row0 + ty * 8;
    const float4* rowp[8];
#pragma unroll
    for (int i = 0; i < 8; ++i) {
        int r = rbase + i;
        r = (r < nrows) ? r : (nrows - 1);
        rowp[i] = X4 + (size_t)r * (K / 4);
    }

    float4 acc[8][TJ];
#pragma unroll
    for (int i = 0; i < 8; ++i)
#pragma unroll
        for (int j = 0; j < TJ; ++j) acc[i][j] = make_float4(0.f, 0.f, 0.f, 0.f);

    float4 aA[8], aB[8];
    load_a8(aA, rowp, 0);
    __syncthreads();

    for (int k4 = 0; k4 < 32; k4 += 2) {
        load_a8(aB, rowp, k4 + 1);
        compute_k4<BN4, TJ>(aA, ws4, k4, tx, acc);
        if (k4 + 2 < 32) load_a8(aA, rowp, k4 + 2);
        compute_k4<BN4, TJ>(aB, ws4, k4 + 1, tx, acc);
    }

    uint2* H8 = reinterpret_cast<uint2*>(H);  // row = 32 uint2
#pragma unroll
    for (int i = 0; i < 8; ++i) {
        int r = rbase + i;
        if (r < nrows) {
            float s = dinv[r];
#pragma unroll
            for (int j = 0; j < TJ; ++j) {
                float4 v = acc[i][j];
                H8[(size_t)r * 32 + j * 16 + tx] =
                    make_uint2(pack_half2(v.x * s, v.y * s), pack_half2(v.z * s, v.w * s));
            }
        }
    }
}

// ---------------------------------------------------------------- GEMM 2
// fp16 in (out1), fp16 out (h2). K = 128, BM = 128, BN = 64. W2 LDS 32 KB.

__global__ __launch_bounds__(256) void gemm2_h16_h16(const __half* __restrict__ Xh,
                                                     const float* __restrict__ W,
                                                     const float* __restrict__ dinv,
                                                     __half* __restrict__ H, int nrows) {
    constexpr int K = 128, BM = 128, BN = 64;
    constexpr int BN4 = BN / 4;               // 16
    __shared__ float4 ws4[K * BN4];           // 32 KB

    const int t = threadIdx.x;
    const int tx = t & 15, ty = t >> 4;
    const int row0 = blockIdx.x * BM;

    const float4* W4 = reinterpret_cast<const float4*>(W);
    for (int i = t; i < K * BN4; i += 256) ws4[i] = W4[i];

    const float4* X4 = reinterpret_cast<const float4*>(Xh);
    const int rbase = row0 + ty * 8;
    const float4* rowp[8];
#pragma unroll
    for (int i = 0; i < 8; ++i) {
        int r = rbase + i;
        r = (r < nrows) ? r : (nrows - 1);
        rowp[i] = X4 + (size_t)r * (K / 8);
    }

    float4 acc[8];
#pragma unroll
    for (int i = 0; i < 8; ++i) acc[i] = make_float4(0.f, 0.f, 0.f, 0.f);

    float4 aA[8], aB[8];
    load_a8(aA, rowp, 0);
    __syncthreads();

    auto compute_k8 = [&](const float4(&A)[8], int c8) {
#pragma unroll
        for (int kk = 0; kk < 8; ++kk) {
            const int k = c8 * 8 + kk;
            float4 b = ws4[k * BN4 + tx];
#pragma unroll
            for (int i = 0; i < 8; ++i) {
                const __half2* hp = reinterpret_cast<const __half2*>(&A[i]);
                __half2 pr = hp[kk >> 1];
                float av = (kk & 1) ? __high2float(pr) : __low2float(pr);
                acc[i].x = fmaf(av, b.x, acc[i].x);
                acc[i].y = fmaf(av, b.y, acc[i].y);
                acc[i].z = fmaf(av, b.z, acc[i].z);
                acc[i].w = fmaf(av, b.w, acc[i].w);
            }
        }
    };

    for (int c8 = 0; c8 < 16; c8 += 2) {
        load_a8(aB, rowp, c8 + 1);
        compute_k8(aA, c8);
        if (c8 + 2 < 16) load_a8(aA, rowp, c8 + 2);
        compute_k8(aB, c8 + 1);
    }

    uint2* H8 = reinterpret_cast<uint2*>(H);  // row = 16 uint2
#pragma unroll
    for (int i = 0; i < 8; ++i) {
        int r = rbase + i;
        if (r < nrows) {
            float s = dinv[r];
            float4 v = acc[i];
            H8[(size_t)r * 16 + tx] =
                make_uint2(pack_half2(v.x * s, v.y * s), pack_half2(v.z * s, v.w * s));
        }
    }
}

// ---------------------------------------------------------------- aggregation
// One wave per node; lanes 0-31 gather edge e, lanes 32-63 edge e+1.
// Scalar (SMEM) index loads via readfirstlane'd offsets. fp32 accumulate.

__global__ __launch_bounds__(256) void k_agg1(const __half* __restrict__ h,
                                              const int* __restrict__ offs,
                                              const int* __restrict__ csc,
                                              const float* __restrict__ dinv,
                                              const float* __restrict__ bias,
                                              __half* __restrict__ out, int n) {
    int node = (blockIdx.x * 256 + threadIdx.x) >> 6;
    if (node >= n) return;
    int lane = threadIdx.x & 63;
    int g = lane >> 5, li = lane & 31;            // li covers cols 4li..4li+3
    const uint2* H8 = reinterpret_cast<const uint2*>(h);  // row = 32 uint2
    int start = __builtin_amdgcn_readfirstlane(offs[node]);
    int end   = __builtin_amdgcn_readfirstlane(offs[node + 1]);
    float4 acc = make_float4(0.f, 0.f, 0.f, 0.f);

    int e = start;
    int emain = start + ((end - start) & ~7);
    for (; e < emain; e += 8) {
        int a0 = csc[e],     a1 = csc[e + 1], a2 = csc[e + 2], a3 = csc[e + 3];
        int a4 = csc[e + 4], a5 = csc[e + 5], a6 = csc[e + 6], a7 = csc[e + 7];
        int s0 = g ? a1 : a0;
        int s1 = g ? a3 : a2;
        int s2 = g ? a5 : a4;
        int s3 = g ? a7 : a6;
        uint2 v0 = H8[(size_t)s0 * 32 + li];
        uint2 v1 = H8[(size_t)s1 * 32 + li];
        uint2 v2 = H8[(size_t)s2 * 32 + li];
        uint2 v3 = H8[(size_t)s3 * 32 + li];
        acc8(acc, v0); acc8(acc, v1); acc8(acc, v2); acc8(acc, v3);
    }
    for (; e < end; e += 2) {
        int sa = csc[e];
        int sb = (e + 1 < end) ? csc[e + 1] : sa;
        int s = g ? sb : sa;
        uint2 v = H8[(size_t)s * 32 + li];
        if (g && (e + 1 >= end)) { v.x = 0u; v.y = 0u; }
        acc8(acc, v);
    }
    // combine the two 32-lane groups
    acc.x += __shfl_xor(acc.x, 32);
    acc.y += __shfl_xor(acc.y, 32);
    acc.z += __shfl_xor(acc.z, 32);
    acc.w += __shfl_xor(acc.w, 32);
    // self loop
    uint2 vs = H8[(size_t)node * 32 + li];
    acc8(acc, vs);
    float di = dinv[node];
    float4 bb = reinterpret_cast<const float4*>(bias)[li];
    float ox = fmaxf(fmaf(acc.x, di, bb.x), 0.f);
    float oy = fmaxf(fmaf(acc.y, di, bb.y), 0.f);
    float oz = fmaxf(fmaf(acc.z, di, bb.z), 0.f);
    float ow = fmaxf(fmaf(acc.w, di, bb.w), 0.f);
    if (g == 0)
        reinterpret_cast<uint2*>(out)[(size_t)node * 32 + li] =
            make_uint2(pack_half2(ox, oy), pack_half2(oz, ow));
}

__global__ __launch_bounds__(256) void k_agg2(const __half* __restrict__ h,
                                              const int* __restrict__ offs,
                                              const int* __restrict__ csc,
                                              const float* __restrict__ dinv,
                                              const float* __restrict__ bias,
                                              float* __restrict__ out, int n) {
    int node = (blockIdx.x * 256 + threadIdx.x) >> 6;
    if (node >= n) return;
    int lane = threadIdx.x & 63;
    int g = lane >> 5, li = lane & 31;            // li covers cols 2li..2li+1
    const unsigned* H4 = reinterpret_cast<const unsigned*>(h);  // row = 32 uints
    int start = __builtin_amdgcn_readfirstlane(offs[node]);
    int end   = __builtin_amdgcn_readfirstlane(offs[node + 1]);
    float2 acc = make_float2(0.f, 0.f);

    int e = start;
    int emain = start + ((end - start) & ~7);
    for (; e < emain; e += 8) {
        int a0 = csc[e],     a1 = csc[e + 1], a2 = csc[e + 2], a3 = csc[e + 3];
        int a4 = csc[e + 4], a5 = csc[e + 5], a6 = csc[e + 6], a7 = csc[e + 7];
        int s0 = g ? a1 : a0;
        int s1 = g ? a3 : a2;
        int s2 = g ? a5 : a4;
        int s3 = g ? a7 : a6;
        unsigned v0 = H4[(size_t)s0 * 32 + li];
        unsigned v1 = H4[(size_t)s1 * 32 + li];
        unsigned v2 = H4[(size_t)s2 * 32 + li];
        unsigned v3 = H4[(size_t)s3 * 32 + li];
        acc4(acc, v0); acc4(acc, v1); acc4(acc, v2); acc4(acc, v3);
    }
    for (; e < end; e += 2) {
        int sa = csc[e];
        int sb = (e + 1 < end) ? csc[e + 1] : sa;
        int s = g ? sb : sa;
        unsigned v = H4[(size_t)s * 32 + li];
        if (g && (e + 1 >= end)) v = 0u;
        acc4(acc, v);
    }
    acc.x += __shfl_xor(acc.x, 32);
    acc.y += __shfl_xor(acc.y, 32);
    acc4(acc, H4[(size_t)node * 32 + li]);  // self loop
    float di = dinv[node];
    float2 bb = reinterpret_cast<const float2*>(bias)[li];
    if (g == 0)
        reinterpret_cast<float2*>(out)[(size_t)node * 32 + li] =
            make_float2(fmaf(acc.x, di, bb.x), fmaf(acc.y, di, bb.y));
}

// ---------------------------------------------------------------- launch

extern "C" void kernel_launch(void* const* d_in, const int* in_sizes, int n_in,
                              void* d_out, int out_size, void* d_ws, size_t ws_size,
                              hipStream_t stream) {
    const float* x  = (const float*)d_in[0];
    const int*   ei = (const int*)d_in[1];
    const float* W1 = (const float*)d_in[2];
    const float* b1 = (const float*)d_in[3];
    const float* W2 = (const float*)d_in[4];
    const float* b2 = (const float*)d_in[5];
    float* out = (float*)d_out;

    const int n = in_sizes[0] / 128;   // 100000 (< 2^24: packed pairs valid)
    const int E = in_sizes[1] / 2;     // 1600000
    const int* src = ei;
    const int* dst = ei + E;
    const int NB = (n + 255) / 256;    // 391 buckets of 256 nodes

    // workspace carving (256B aligned)
    char* p = (char*)d_ws;
    auto carve = [&](size_t bytes) -> void* {
        void* r = (void*)p;
        p += (bytes + 255) & ~(size_t)255;
        return r;
    };
    float* dinv    = (float*)carve((size_t)n * 4);
    int*   offs    = (int*)carve((size_t)(n + 1) * 4);
    int*   bcnt    = (int*)carve((size_t)(NB + 1) * 4);
    int*   boffs   = (int*)carve((size_t)(NB + 1) * 4);
    int*   bcur    = (int*)carve((size_t)(NB + 1) * 4);
    int*   csc     = (int*)carve((size_t)E * 4);
    __half* h1     = (__half*)carve((size_t)n * 128 * 2);   // 25.6 MB
    __half* out1   = (__half*)carve((size_t)n * 128 * 2);   // 25.6 MB
    unsigned* pairs = (unsigned*)h1;  // E*4 = 6.4 MB; dead before gemm1
    __half* h2     = h1;              // h1 dead after layer-1 aggregation

    const int gemm_blocks = (n + 127) / 128;
    const int gagg = (n + 3) / 4;
    const int GB   = 256;                // bucket-pass blocks
    const int epb  = (E + GB - 1) / GB;  // edges per block

    // ---- CSC build (bucketed counting sort by dst) ----
    k_zero<<<(NB + 256) / 256, 256, 0, stream>>>(bcnt, NB + 1);
    k_bhist<<<GB, 256, 0, stream>>>(dst, E, bcnt, NB, epb);
    k_bscan<<<1, 512, 0, stream>>>(bcnt, boffs, bcur, NB, E);
    k_bscatter<<<GB, 256, 0, stream>>>(src, dst, E, bcur, pairs, NB, epb);
    k_bfinal<<<NB, 256, 0, stream>>>(pairs, boffs, dinv, offs, csc, n, E, NB);

    // ---- layer 1: h1 = (x @ W1) * dinv ; out1 = relu(agg(h1)*dinv + b1) ----
    gemm1_f32_h16<<<gemm_blocks, 256, 0, stream>>>(x, W1, dinv, h1, n);
    k_agg1<<<gagg, 256, 0, stream>>>(h1, offs, csc, dinv, b1, out1, n);

    // ---- layer 2: h2 = (out1 @ W2) * dinv ; out = agg(h2)*dinv + b2 ----
    gemm2_h16_h16<<<gemm_blocks, 256, 0, stream>>>(out1, W2, dinv, h2, n);
    k_agg2<<<gagg, 256, 0, stream>>>(h2, offs, csc, dinv, b2, out, n);
}

// Round 5
// 191.728 us; speedup vs baseline: 2.8802x; 1.3703x over previous
//
#include <hip/hip_runtime.h>
#include <hip/hip_fp16.h>

typedef _Float16 half8 __attribute__((ext_vector_type(8)));
typedef float f32x4 __attribute__((ext_vector_type(4)));

// ---------------------------------------------------------------- helpers

__device__ __forceinline__ unsigned pack_half2(float x, float y) {
    __half2 h = __float22half2_rn(make_float2(x, y));
    return *reinterpret_cast<unsigned*>(&h);
}
__device__ __forceinline__ float2 up2(unsigned u) {
    __half2 h = *reinterpret_cast<__half2*>(&u);
    return __half22float2(h);
}
__device__ __forceinline__ void acc8(float4& a, uint2 v) {
    float2 p = up2(v.x), q = up2(v.y);
    a.x += p.x; a.y += p.y; a.z += q.x; a.w += q.y;
}
__device__ __forceinline__ void acc4(float2& a, unsigned v) {
    float2 p = up2(v);
    a.x += p.x; a.y += p.y;
}

// ---------------------------------------------------------------- utilities

__global__ __launch_bounds__(256) void k_zero(int* p, int n) {
    int i = blockIdx.x * 256 + threadIdx.x;
    if (i < n) p[i] = 0;
}

// W1 [k][128] f32 -> Wt1 [col][k] f16 ; W2 [k][64] f32 -> Wt2 [col][k] f16
__global__ __launch_bounds__(256) void k_wconv(const float* __restrict__ W1,
                                               const float* __restrict__ W2,
                                               __half* __restrict__ Wt1,
                                               __half* __restrict__ Wt2) {
    int i = blockIdx.x * 256 + threadIdx.x;
    if (i < 16384) {
        int col = i >> 7, k = i & 127;
        Wt1[i] = __float2half(W1[(k << 7) + col]);
    } else if (i < 24576) {
        int j = i - 16384;
        int col = j >> 7, k = j & 127;
        Wt2[j] = __float2half(W2[(k << 6) + col]);
    }
}

// ------------------------------------------------ bucketed CSC construction
// Bucket = dst >> 8 (256 nodes). NB <= 512. Pair packed: src(24b) | dstLow8(8b).

__global__ __launch_bounds__(256) void k_bhist(const int* __restrict__ dst, int E,
                                               int* __restrict__ bcnt, int NB, int epb) {
    __shared__ int h[512];
    for (int i = threadIdx.x; i < NB; i += 256) h[i] = 0;
    __syncthreads();
    int lo = blockIdx.x * epb;
    int hi = min(lo + epb, E);
    for (int e = lo + threadIdx.x; e < hi; e += 256)
        atomicAdd(&h[dst[e] >> 8], 1);
    __syncthreads();
    for (int i = threadIdx.x; i < NB; i += 256)
        if (h[i]) atomicAdd(&bcnt[i], h[i]);
}

__global__ __launch_bounds__(512) void k_bscan(const int* __restrict__ bcnt,
                                               int* __restrict__ boffs,
                                               int* __restrict__ bcur, int NB, int E) {
    __shared__ int sm[512];
    int t = threadIdx.x;
    int v = (t < NB) ? bcnt[t] : 0;
    sm[t] = v;
    __syncthreads();
    for (int d = 1; d < 512; d <<= 1) {
        int xv = (t >= d) ? sm[t - d] : 0;
        __syncthreads();
        sm[t] += xv;
        __syncthreads();
    }
    if (t < NB) { boffs[t] = sm[t] - v; bcur[t] = sm[t] - v; }
    if (t == 0) boffs[NB] = E;
}

__global__ __launch_bounds__(256) void k_bscatter(const int* __restrict__ src,
                                                  const int* __restrict__ dst, int E,
                                                  int* __restrict__ bcur,
                                                  unsigned* __restrict__ pairs,
                                                  int NB, int epb) {
    __shared__ int h[512];
    __shared__ int base[512];
    for (int i = threadIdx.x; i < NB; i += 256) h[i] = 0;
    __syncthreads();
    int lo = blockIdx.x * epb;
    int hi = min(lo + epb, E);
    for (int e = lo + threadIdx.x; e < hi; e += 256)
        atomicAdd(&h[dst[e] >> 8], 1);
    __syncthreads();
    for (int i = threadIdx.x; i < NB; i += 256) {
        int c = h[i];
        base[i] = c ? atomicAdd(&bcur[i], c) : 0;
        h[i] = 0;  // becomes local cursor
    }
    __syncthreads();
    for (int e = lo + threadIdx.x; e < hi; e += 256) {
        int s = src[e], d = dst[e];
        int b = d >> 8;
        int r = atomicAdd(&h[b], 1);
        pairs[base[b] + r] = (unsigned)s | ((unsigned)(d & 255) << 24);
    }
}

// per-bucket: counts -> dinv, LDS exclusive scan -> offs, then csc placement
__global__ __launch_bounds__(256) void k_bfinal(const unsigned* __restrict__ pairs,
                                                const int* __restrict__ boffs,
                                                float* __restrict__ dinv,
                                                int* __restrict__ offs,
                                                int* __restrict__ csc,
                                                int n, int E, int NB) {
    __shared__ int cnt[256];
    __shared__ int scn[256];
    int b = blockIdx.x, t = threadIdx.x;
    cnt[t] = 0;
    __syncthreads();
    int lo = boffs[b], hi = boffs[b + 1];
    for (int e = lo + t; e < hi; e += 256)
        atomicAdd(&cnt[pairs[e] >> 24], 1);
    __syncthreads();
    int c = cnt[t];
    int node = b * 256 + t;
    if (node < n) dinv[node] = rsqrtf((float)(c + 1));  // +1 self-loop
    scn[t] = c;
    __syncthreads();
    for (int d = 1; d < 256; d <<= 1) {
        int xv = (t >= d) ? scn[t - d] : 0;
        __syncthreads();
        scn[t] += xv;
        __syncthreads();
    }
    int myoff = lo + scn[t] - c;
    if (node < n) offs[node] = myoff;
    if (b == NB - 1 && t == 255) offs[n] = E;
    cnt[t] = myoff;  // reuse as absolute cursor
    __syncthreads();
    for (int e = lo + t; e < hi; e += 256) {
        unsigned p = pairs[e];
        int pos = atomicAdd(&cnt[p >> 24], 1);
        csc[pos] = (int)(p & 0x00FFFFFFu);
    }
}

// ---------------------------------------------------------------- MFMA GEMMs
// mfma_f32_16x16x32_f16 layouts (gfx950):
//   A: lane l holds A[row = l&15][k = (l>>4)*8 + j], j=0..7
//   B: lane l holds B[k = (l>>4)*8 + j][col = l&15]
//   C: lane l, reg r -> row = (l>>4)*4 + r, col = l&15   (m89-verified)
// Block = 4 waves x 16 rows = 64 rows. W^T staged in LDS as half8 chunks,
// chunk index XOR-swizzled by (col&7) to break the 256B-stride bank pattern.

__global__ __launch_bounds__(256) void gemm1_mfma(const float* __restrict__ X,
                                                  const __half* __restrict__ Wt,  // [128][128] f16
                                                  const float* __restrict__ dinv,
                                                  __half* __restrict__ H, int nrows) {
    __shared__ half8 wt[2048];  // 32 KB
    const int t = threadIdx.x;

    const half8* Wg = reinterpret_cast<const half8*>(Wt);
    for (int i = t; i < 2048; i += 256) {
        int col = i >> 4, kc = i & 15;
        wt[(col << 4) | (kc ^ (col & 7))] = Wg[i];
    }

    const int wid = t >> 6, lane = t & 63;
    const int li = lane & 15, kq = lane >> 4;
    const int rbase = blockIdx.x * 64 + wid * 16;
    int row = rbase + li;
    int rowc = min(row, nrows - 1);

    // A fragments: 8 contiguous fp32 -> 8 halves, per k-step
    const float4* X4 = reinterpret_cast<const float4*>(X) + (size_t)rowc * 32;
    half8 a[4];
#pragma unroll
    for (int kk = 0; kk < 4; ++kk) {
        float4 lo = X4[kk * 8 + kq * 2];
        float4 hi = X4[kk * 8 + kq * 2 + 1];
        half8 v;
        v[0] = (_Float16)lo.x; v[1] = (_Float16)lo.y;
        v[2] = (_Float16)lo.z; v[3] = (_Float16)lo.w;
        v[4] = (_Float16)hi.x; v[5] = (_Float16)hi.y;
        v[6] = (_Float16)hi.z; v[7] = (_Float16)hi.w;
        a[kk] = v;
    }
    __syncthreads();

    f32x4 acc[8];
#pragma unroll
    for (int ct = 0; ct < 8; ++ct) acc[ct] = (f32x4){0.f, 0.f, 0.f, 0.f};

#pragma unroll
    for (int ct = 0; ct < 8; ++ct) {
        int col = ct * 16 + li;
        int cbase = col << 4, sw = col & 7;
#pragma unroll
        for (int kk = 0; kk < 4; ++kk) {
            half8 b = wt[cbase | ((kk * 4 + kq) ^ sw)];
            acc[ct] = __builtin_amdgcn_mfma_f32_16x16x32_f16(a[kk], b, acc[ct], 0, 0, 0);
        }
    }

    const int r0 = rbase + kq * 4;
#pragma unroll
    for (int r = 0; r < 4; ++r) {
        int rr = r0 + r;
        if (rr < nrows) {
            float s = dinv[rr];
            __half* orow = H + (size_t)rr * 128;
#pragma unroll
            for (int ct = 0; ct < 8; ++ct)
                orow[ct * 16 + li] = __float2half(acc[ct][r] * s);
        }
    }
}

__global__ __launch_bounds__(256) void gemm2_mfma(const __half* __restrict__ Xh,
                                                  const __half* __restrict__ Wt,  // [64][128] f16
                                                  const float* __restrict__ dinv,
                                                  __half* __restrict__ H, int nrows) {
    __shared__ half8 wt[1024];  // 16 KB
    const int t = threadIdx.x;

    const half8* Wg = reinterpret_cast<const half8*>(Wt);
    for (int i = t; i < 1024; i += 256) {
        int col = i >> 4, kc = i & 15;
        wt[(col << 4) | (kc ^ (col & 7))] = Wg[i];
    }

    const int wid = t >> 6, lane = t & 63;
    const int li = lane & 15, kq = lane >> 4;
    const int rbase = blockIdx.x * 64 + wid * 16;
    int row = rbase + li;
    int rowc = min(row, nrows - 1);

    const half8* A8 = reinterpret_cast<const half8*>(Xh) + (size_t)rowc * 16;
    half8 a[4];
#pragma unroll
    for (int kk = 0; kk < 4; ++kk) a[kk] = A8[kk * 4 + kq];
    __syncthreads();

    f32x4 acc[4];
#pragma unroll
    for (int ct = 0; ct < 4; ++ct) acc[ct] = (f32x4){0.f, 0.f, 0.f, 0.f};

#pragma unroll
    for (int ct = 0; ct < 4; ++ct) {
        int col = ct * 16 + li;
        int cbase = col << 4, sw = col & 7;
#pragma unroll
        for (int kk = 0; kk < 4; ++kk) {
            half8 b = wt[cbase | ((kk * 4 + kq) ^ sw)];
            acc[ct] = __builtin_amdgcn_mfma_f32_16x16x32_f16(a[kk], b, acc[ct], 0, 0, 0);
        }
    }

    const int r0 = rbase + kq * 4;
#pragma unroll
    for (int r = 0; r < 4; ++r) {
        int rr = r0 + r;
        if (rr < nrows) {
            float s = dinv[rr];
            __half* orow = H + (size_t)rr * 64;
#pragma unroll
            for (int ct = 0; ct < 4; ++ct)
                orow[ct * 16 + li] = __float2half(acc[ct][r] * s);
        }
    }
}

// ---------------------------------------------------------------- aggregation
// One wave per node; lanes 0-31 gather edge e, lanes 32-63 edge e+1.
// Scalar index loads via readfirstlane'd offsets. fp32 accumulate.

__global__ __launch_bounds__(256) void k_agg1(const __half* __restrict__ h,
                                              const int* __restrict__ offs,
                                              const int* __restrict__ csc,
                                              const float* __restrict__ dinv,
                                              const float* __restrict__ bias,
                                              __half* __restrict__ out, int n) {
    int node = (blockIdx.x * 256 + threadIdx.x) >> 6;
    if (node >= n) return;
    int lane = threadIdx.x & 63;
    int g = lane >> 5, li = lane & 31;            // li covers cols 4li..4li+3
    const uint2* H8 = reinterpret_cast<const uint2*>(h);  // row = 32 uint2
    int start = __builtin_amdgcn_readfirstlane(offs[node]);
    int end   = __builtin_amdgcn_readfirstlane(offs[node + 1]);
    float4 acc = make_float4(0.f, 0.f, 0.f, 0.f);

    int e = start;
    int emain = start + ((end - start) & ~7);
    for (; e < emain; e += 8) {
        int a0 = csc[e],     a1 = csc[e + 1], a2 = csc[e + 2], a3 = csc[e + 3];
        int a4 = csc[e + 4], a5 = csc[e + 5], a6 = csc[e + 6], a7 = csc[e + 7];
        int s0 = g ? a1 : a0;
        int s1 = g ? a3 : a2;
        int s2 = g ? a5 : a4;
        int s3 = g ? a7 : a6;
        uint2 v0 = H8[(size_t)s0 * 32 + li];
        uint2 v1 = H8[(size_t)s1 * 32 + li];
        uint2 v2 = H8[(size_t)s2 * 32 + li];
        uint2 v3 = H8[(size_t)s3 * 32 + li];
        acc8(acc, v0); acc8(acc, v1); acc8(acc, v2); acc8(acc, v3);
    }
    for (; e < end; e += 2) {
        int sa = csc[e];
        int sb = (e + 1 < end) ? csc[e + 1] : sa;
        int s = g ? sb : sa;
        uint2 v = H8[(size_t)s * 32 + li];
        if (g && (e + 1 >= end)) { v.x = 0u; v.y = 0u; }
        acc8(acc, v);
    }
    acc.x += __shfl_xor(acc.x, 32);
    acc.y += __shfl_xor(acc.y, 32);
    acc.z += __shfl_xor(acc.z, 32);
    acc.w += __shfl_xor(acc.w, 32);
    uint2 vs = H8[(size_t)node * 32 + li];  // self loop
    acc8(acc, vs);
    float di = dinv[node];
    float4 bb = reinterpret_cast<const float4*>(bias)[li];
    float ox = fmaxf(fmaf(acc.x, di, bb.x), 0.f);
    float oy = fmaxf(fmaf(acc.y, di, bb.y), 0.f);
    float oz = fmaxf(fmaf(acc.z, di, bb.z), 0.f);
    float ow = fmaxf(fmaf(acc.w, di, bb.w), 0.f);
    if (g == 0)
        reinterpret_cast<uint2*>(out)[(size_t)node * 32 + li] =
            make_uint2(pack_half2(ox, oy), pack_half2(oz, ow));
}

__global__ __launch_bounds__(256) void k_agg2(const __half* __restrict__ h,
                                              const int* __restrict__ offs,
                                              const int* __restrict__ csc,
                                              const float* __restrict__ dinv,
                                              const float* __restrict__ bias,
                                              float* __restrict__ out, int n) {
    int node = (blockIdx.x * 256 + threadIdx.x) >> 6;
    if (node >= n) return;
    int lane = threadIdx.x & 63;
    int g = lane >> 5, li = lane & 31;            // li covers cols 2li..2li+1
    const unsigned* H4 = reinterpret_cast<const unsigned*>(h);  // row = 32 uints
    int start = __builtin_amdgcn_readfirstlane(offs[node]);
    int end   = __builtin_amdgcn_readfirstlane(offs[node + 1]);
    float2 acc = make_float2(0.f, 0.f);

    int e = start;
    int emain = start + ((end - start) & ~7);
    for (; e < emain; e += 8) {
        int a0 = csc[e],     a1 = csc[e + 1], a2 = csc[e + 2], a3 = csc[e + 3];
        int a4 = csc[e + 4], a5 = csc[e + 5], a6 = csc[e + 6], a7 = csc[e + 7];
        int s0 = g ? a1 : a0;
        int s1 = g ? a3 : a2;
        int s2 = g ? a5 : a4;
        int s3 = g ? a7 : a6;
        unsigned v0 = H4[(size_t)s0 * 32 + li];
        unsigned v1 = H4[(size_t)s1 * 32 + li];
        unsigned v2 = H4[(size_t)s2 * 32 + li];
        unsigned v3 = H4[(size_t)s3 * 32 + li];
        acc4(acc, v0); acc4(acc, v1); acc4(acc, v2); acc4(acc, v3);
    }
    for (; e < end; e += 2) {
        int sa = csc[e];
        int sb = (e + 1 < end) ? csc[e + 1] : sa;
        int s = g ? sb : sa;
        unsigned v = H4[(size_t)s * 32 + li];
        if (g && (e + 1 >= end)) v = 0u;
        acc4(acc, v);
    }
    acc.x += __shfl_xor(acc.x, 32);
    acc.y += __shfl_xor(acc.y, 32);
    acc4(acc, H4[(size_t)node * 32 + li]);  // self loop
    float di = dinv[node];
    float2 bb = reinterpret_cast<const float2*>(bias)[li];
    if (g == 0)
        reinterpret_cast<float2*>(out)[(size_t)node * 32 + li] =
            make_float2(fmaf(acc.x, di, bb.x), fmaf(acc.y, di, bb.y));
}

// ---------------------------------------------------------------- launch

extern "C" void kernel_launch(void* const* d_in, const int* in_sizes, int n_in,
                              void* d_out, int out_size, void* d_ws, size_t ws_size,
                              hipStream_t stream) {
    const float* x  = (const float*)d_in[0];
    const int*   ei = (const int*)d_in[1];
    const float* W1 = (const float*)d_in[2];
    const float* b1 = (const float*)d_in[3];
    const float* W2 = (const float*)d_in[4];
    const float* b2 = (const float*)d_in[5];
    float* out = (float*)d_out;

    const int n = in_sizes[0] / 128;   // 100000 (< 2^24: packed pairs valid)
    const int E = in_sizes[1] / 2;     // 1600000
    const int* src = ei;
    const int* dst = ei + E;
    const int NB = (n + 255) / 256;    // 391 buckets of 256 nodes

    // workspace carving (256B aligned)
    char* p = (char*)d_ws;
    auto carve = [&](size_t bytes) -> void* {
        void* r = (void*)p;
        p += (bytes + 255) & ~(size_t)255;
        return r;
    };
    float* dinv    = (float*)carve((size_t)n * 4);
    int*   offs    = (int*)carve((size_t)(n + 1) * 4);
    int*   bcnt    = (int*)carve((size_t)(NB + 1) * 4);
    int*   boffs   = (int*)carve((size_t)(NB + 1) * 4);
    int*   bcur    = (int*)carve((size_t)(NB + 1) * 4);
    __half* Wt1h   = (__half*)carve(16384 * 2);
    __half* Wt2h   = (__half*)carve(8192 * 2);
    int*   csc     = (int*)carve((size_t)E * 4);
    __half* h1     = (__half*)carve((size_t)n * 128 * 2);   // 25.6 MB
    __half* out1   = (__half*)carve((size_t)n * 128 * 2);   // 25.6 MB
    unsigned* pairs = (unsigned*)h1;  // E*4 = 6.4 MB; dead before gemm1
    __half* h2     = h1;              // h1 dead after layer-1 aggregation

    const int gmm  = (n + 63) / 64;       // MFMA gemm blocks (64 rows each)
    const int gagg = (n + 3) / 4;
    const int GB   = 256;                 // bucket-pass blocks
    const int epb  = (E + GB - 1) / GB;   // edges per block

    // ---- weight convert+transpose (independent) ----
    k_wconv<<<96, 256, 0, stream>>>(W1, W2, Wt1h, Wt2h);

    // ---- CSC build (bucketed counting sort by dst) ----
    k_zero<<<(NB + 256) / 256, 256, 0, stream>>>(bcnt, NB + 1);
    k_bhist<<<GB, 256, 0, stream>>>(dst, E, bcnt, NB, epb);
    k_bscan<<<1, 512, 0, stream>>>(bcnt, boffs, bcur, NB, E);
    k_bscatter<<<GB, 256, 0, stream>>>(src, dst, E, bcur, pairs, NB, epb);
    k_bfinal<<<NB, 256, 0, stream>>>(pairs, boffs, dinv, offs, csc, n, E, NB);

    // ---- layer 1: h1 = f16((x @ W1) * dinv) ; out1 = f16(relu(agg*dinv + b1)) ----
    gemm1_mfma<<<gmm, 256, 0, stream>>>(x, Wt1h, dinv, h1, n);
    k_agg1<<<gagg, 256, 0, stream>>>(h1, offs, csc, dinv, b1, out1, n);

    // ---- layer 2: h2 = f16((out1 @ W2) * dinv) ; out = agg*dinv + b2 ----
    gemm2_mfma<<<gmm, 256, 0, stream>>>(out1, Wt2h, dinv, h2, n);
    k_agg2<<<gagg, 256, 0, stream>>>(h2, offs, csc, dinv, b2, out, n);
}

// Round 6
// 188.543 us; speedup vs baseline: 2.9289x; 1.0169x over previous
//
#include <hip/hip_runtime.h>
#include <hip/hip_fp16.h>

typedef _Float16 half8 __attribute__((ext_vector_type(8)));
typedef float f32x4 __attribute__((ext_vector_type(4)));

// ---------------------------------------------------------------- helpers

__device__ __forceinline__ unsigned pack_half2(float x, float y) {
    __half2 h = __float22half2_rn(make_float2(x, y));
    return *reinterpret_cast<unsigned*>(&h);
}
__device__ __forceinline__ float2 up2(unsigned u) {
    __half2 h = *reinterpret_cast<__half2*>(&u);
    return __half22float2(h);
}
__device__ __forceinline__ void acc8(float4& a, uint2 v) {
    float2 p = up2(v.x), q = up2(v.y);
    a.x += p.x; a.y += p.y; a.z += q.x; a.w += q.y;
}
__device__ __forceinline__ void acc4(float2& a, unsigned v) {
    float2 p = up2(v);
    a.x += p.x; a.y += p.y;
}
// 32-bit voffset loads (base uniform -> saddr form)
__device__ __forceinline__ uint2 ld8(const char* __restrict__ b, unsigned off) {
    return *reinterpret_cast<const uint2*>(b + off);
}
__device__ __forceinline__ unsigned ld4(const char* __restrict__ b, unsigned off) {
    return *reinterpret_cast<const unsigned*>(b + off);
}

// ---------------------------------------------------------------- fused init
// W1 [k][128] f32 -> Wt1 [col][k] f16 ; W2 [k][64] f32 -> Wt2 [col][k] f16
// + zero bcnt (needed before k_bhist)

__global__ __launch_bounds__(256) void k_wconv(const float* __restrict__ W1,
                                               const float* __restrict__ W2,
                                               __half* __restrict__ Wt1,
                                               __half* __restrict__ Wt2,
                                               int* __restrict__ bcnt, int nbz) {
    int i = blockIdx.x * 256 + threadIdx.x;
    if (i < nbz) bcnt[i] = 0;
    if (i < 16384) {
        int col = i >> 7, k = i & 127;
        Wt1[i] = __float2half(W1[(k << 7) + col]);
    } else if (i < 24576) {
        int j = i - 16384;
        int col = j >> 7, k = j & 127;
        Wt2[j] = __float2half(W2[(k << 6) + col]);
    }
}

// ------------------------------------------------ bucketed CSC construction
// Bucket = dst >> 8 (256 nodes). NB <= 512. Pair packed: src(24b) | dstLow8(8b).

__global__ __launch_bounds__(256) void k_bhist(const int* __restrict__ dst, int E,
                                               int* __restrict__ bcnt, int NB, int epb) {
    __shared__ int h[512];
    for (int i = threadIdx.x; i < NB; i += 256) h[i] = 0;
    __syncthreads();
    int lo = blockIdx.x * epb;
    int hi = min(lo + epb, E);
    for (int e = lo + threadIdx.x; e < hi; e += 256)
        atomicAdd(&h[dst[e] >> 8], 1);
    __syncthreads();
    for (int i = threadIdx.x; i < NB; i += 256)
        if (h[i]) atomicAdd(&bcnt[i], h[i]);
}

__global__ __launch_bounds__(512) void k_bscan(const int* __restrict__ bcnt,
                                               int* __restrict__ boffs,
                                               int* __restrict__ bcur, int NB, int E) {
    __shared__ int sm[512];
    int t = threadIdx.x;
    int v = (t < NB) ? bcnt[t] : 0;
    sm[t] = v;
    __syncthreads();
    for (int d = 1; d < 512; d <<= 1) {
        int xv = (t >= d) ? sm[t - d] : 0;
        __syncthreads();
        sm[t] += xv;
        __syncthreads();
    }
    if (t < NB) { boffs[t] = sm[t] - v; bcur[t] = sm[t] - v; }
    if (t == 0) boffs[NB] = E;
}

__global__ __launch_bounds__(256) void k_bscatter(const int* __restrict__ src,
                                                  const int* __restrict__ dst, int E,
                                                  int* __restrict__ bcur,
                                                  unsigned* __restrict__ pairs,
                                                  int NB, int epb) {
    __shared__ int h[512];
    __shared__ int base[512];
    for (int i = threadIdx.x; i < NB; i += 256) h[i] = 0;
    __syncthreads();
    int lo = blockIdx.x * epb;
    int hi = min(lo + epb, E);
    for (int e = lo + threadIdx.x; e < hi; e += 256)
        atomicAdd(&h[dst[e] >> 8], 1);
    __syncthreads();
    for (int i = threadIdx.x; i < NB; i += 256) {
        int c = h[i];
        base[i] = c ? atomicAdd(&bcur[i], c) : 0;
        h[i] = 0;  // becomes local cursor
    }
    __syncthreads();
    for (int e = lo + threadIdx.x; e < hi; e += 256) {
        int s = src[e], d = dst[e];
        int b = d >> 8;
        int r = atomicAdd(&h[b], 1);
        pairs[base[b] + r] = (unsigned)s | ((unsigned)(d & 255) << 24);
    }
}

// per-bucket: counts -> dinv, LDS exclusive scan -> offs, then csc placement
__global__ __launch_bounds__(256) void k_bfinal(const unsigned* __restrict__ pairs,
                                                const int* __restrict__ boffs,
                                                float* __restrict__ dinv,
                                                int* __restrict__ offs,
                                                int* __restrict__ csc,
                                                int n, int E, int NB) {
    __shared__ int cnt[256];
    __shared__ int scn[256];
    int b = blockIdx.x, t = threadIdx.x;
    cnt[t] = 0;
    __syncthreads();
    int lo = boffs[b], hi = boffs[b + 1];
    for (int e = lo + t; e < hi; e += 256)
        atomicAdd(&cnt[pairs[e] >> 24], 1);
    __syncthreads();
    int c = cnt[t];
    int node = b * 256 + t;
    if (node < n) dinv[node] = rsqrtf((float)(c + 1));  // +1 self-loop
    scn[t] = c;
    __syncthreads();
    for (int d = 1; d < 256; d <<= 1) {
        int xv = (t >= d) ? scn[t - d] : 0;
        __syncthreads();
        scn[t] += xv;
        __syncthreads();
    }
    int myoff = lo + scn[t] - c;
    if (node < n) offs[node] = myoff;
    if (b == NB - 1 && t == 255) offs[n] = E;
    cnt[t] = myoff;  // reuse as absolute cursor
    __syncthreads();
    for (int e = lo + t; e < hi; e += 256) {
        unsigned p = pairs[e];
        int pos = atomicAdd(&cnt[p >> 24], 1);
        csc[pos] = (int)(p & 0x00FFFFFFu);
    }
}

// ---------------------------------------------------------------- MFMA GEMMs
// mfma_f32_16x16x32_f16 layouts (gfx950):
//   A: lane l holds A[row = l&15][k = (l>>4)*8 + j], j=0..7
//   B: lane l holds B[k = (l>>4)*8 + j][col = l&15]
//   C: lane l, reg r -> row = (l>>4)*4 + r, col = l&15
// Block = 4 waves x 16 rows = 64 rows. W^T staged in LDS as half8 chunks,
// chunk index XOR-swizzled by (col&7).

__global__ __launch_bounds__(256) void gemm1_mfma(const float* __restrict__ X,
                                                  const __half* __restrict__ Wt,  // [128][128] f16
                                                  const float* __restrict__ dinv,
                                                  __half* __restrict__ H, int nrows) {
    __shared__ half8 wt[2048];  // 32 KB
    const int t = threadIdx.x;

    const half8* Wg = reinterpret_cast<const half8*>(Wt);
    for (int i = t; i < 2048; i += 256) {
        int col = i >> 4, kc = i & 15;
        wt[(col << 4) | (kc ^ (col & 7))] = Wg[i];
    }

    const int wid = t >> 6, lane = t & 63;
    const int li = lane & 15, kq = lane >> 4;
    const int rbase = blockIdx.x * 64 + wid * 16;
    int row = rbase + li;
    int rowc = min(row, nrows - 1);

    const float4* X4 = reinterpret_cast<const float4*>(X) + (size_t)rowc * 32;
    half8 a[4];
#pragma unroll
    for (int kk = 0; kk < 4; ++kk) {
        float4 lo = X4[kk * 8 + kq * 2];
        float4 hi = X4[kk * 8 + kq * 2 + 1];
        half8 v;
        v[0] = (_Float16)lo.x; v[1] = (_Float16)lo.y;
        v[2] = (_Float16)lo.z; v[3] = (_Float16)lo.w;
        v[4] = (_Float16)hi.x; v[5] = (_Float16)hi.y;
        v[6] = (_Float16)hi.z; v[7] = (_Float16)hi.w;
        a[kk] = v;
    }
    __syncthreads();

    f32x4 acc[8];
#pragma unroll
    for (int ct = 0; ct < 8; ++ct) acc[ct] = (f32x4){0.f, 0.f, 0.f, 0.f};

#pragma unroll
    for (int ct = 0; ct < 8; ++ct) {
        int col = ct * 16 + li;
        int cbase = col << 4, sw = col & 7;
#pragma unroll
        for (int kk = 0; kk < 4; ++kk) {
            half8 b = wt[cbase | ((kk * 4 + kq) ^ sw)];
            acc[ct] = __builtin_amdgcn_mfma_f32_16x16x32_f16(a[kk], b, acc[ct], 0, 0, 0);
        }
    }

    const int r0 = rbase + kq * 4;
#pragma unroll
    for (int r = 0; r < 4; ++r) {
        int rr = r0 + r;
        if (rr < nrows) {
            float s = dinv[rr];
            __half* orow = H + (size_t)rr * 128;
#pragma unroll
            for (int ct = 0; ct < 8; ++ct)
                orow[ct * 16 + li] = __float2half(acc[ct][r] * s);
        }
    }
}

__global__ __launch_bounds__(256) void gemm2_mfma(const __half* __restrict__ Xh,
                                                  const __half* __restrict__ Wt,  // [64][128] f16
                                                  const float* __restrict__ dinv,
                                                  __half* __restrict__ H, int nrows) {
    __shared__ half8 wt[1024];  // 16 KB
    const int t = threadIdx.x;

    const half8* Wg = reinterpret_cast<const half8*>(Wt);
    for (int i = t; i < 1024; i += 256) {
        int col = i >> 4, kc = i & 15;
        wt[(col << 4) | (kc ^ (col & 7))] = Wg[i];
    }

    const int wid = t >> 6, lane = t & 63;
    const int li = lane & 15, kq = lane >> 4;
    const int rbase = blockIdx.x * 64 + wid * 16;
    int row = rbase + li;
    int rowc = min(row, nrows - 1);

    const half8* A8 = reinterpret_cast<const half8*>(Xh) + (size_t)rowc * 16;
    half8 a[4];
#pragma unroll
    for (int kk = 0; kk < 4; ++kk) a[kk] = A8[kk * 4 + kq];
    __syncthreads();

    f32x4 acc[4];
#pragma unroll
    for (int ct = 0; ct < 4; ++ct) acc[ct] = (f32x4){0.f, 0.f, 0.f, 0.f};

#pragma unroll
    for (int ct = 0; ct < 4; ++ct) {
        int col = ct * 16 + li;
        int cbase = col << 4, sw = col & 7;
#pragma unroll
        for (int kk = 0; kk < 4; ++kk) {
            half8 b = wt[cbase | ((kk * 4 + kq) ^ sw)];
            acc[ct] = __builtin_amdgcn_mfma_f32_16x16x32_f16(a[kk], b, acc[ct], 0, 0, 0);
        }
    }

    const int r0 = rbase + kq * 4;
#pragma unroll
    for (int r = 0; r < 4; ++r) {
        int rr = r0 + r;
        if (rr < nrows) {
            float s = dinv[rr];
            __half* orow = H + (size_t)rr * 64;
#pragma unroll
            for (int ct = 0; ct < 4; ++ct)
                orow[ct * 16 + li] = __float2half(acc[ct][r] * s);
        }
    }
}

// ---------------------------------------------------------------- aggregation
// One wave per node; lanes 0-31 gather edge e, lanes 32-63 edge e+1.
// Scalar index loads via readfirstlane'd offsets; 32-bit saddr+voffset gathers.

__global__ __launch_bounds__(256) void k_agg1(const __half* __restrict__ h,
                                              const int* __restrict__ offs,
                                              const int* __restrict__ csc,
                                              const float* __restrict__ dinv,
                                              const float* __restrict__ bias,
                                              __half* __restrict__ out, int n) {
    int node = (blockIdx.x * 256 + threadIdx.x) >> 6;
    if (node >= n) return;
    int lane = threadIdx.x & 63;
    int g = lane >> 5, li = lane & 31;            // li covers cols 4li..4li+3
    const char* hb = reinterpret_cast<const char*>(h);  // row = 256 B
    const unsigned loff = (unsigned)li << 3;
    int start = __builtin_amdgcn_readfirstlane(offs[node]);
    int end   = __builtin_amdgcn_readfirstlane(offs[node + 1]);
    float4 acc = make_float4(0.f, 0.f, 0.f, 0.f);

    int e = start;
    int emain = start + ((end - start) & ~7);
    for (; e < emain; e += 8) {
        int a0 = csc[e],     a1 = csc[e + 1], a2 = csc[e + 2], a3 = csc[e + 3];
        int a4 = csc[e + 4], a5 = csc[e + 5], a6 = csc[e + 6], a7 = csc[e + 7];
        unsigned o0 = (((unsigned)(g ? a1 : a0)) << 8) | loff;
        unsigned o1 = (((unsigned)(g ? a3 : a2)) << 8) | loff;
        unsigned o2 = (((unsigned)(g ? a5 : a4)) << 8) | loff;
        unsigned o3 = (((unsigned)(g ? a7 : a6)) << 8) | loff;
        uint2 v0 = ld8(hb, o0);
        uint2 v1 = ld8(hb, o1);
        uint2 v2 = ld8(hb, o2);
        uint2 v3 = ld8(hb, o3);
        acc8(acc, v0); acc8(acc, v1); acc8(acc, v2); acc8(acc, v3);
    }
    for (; e < end; e += 2) {
        int sa = csc[e];
        int sb = (e + 1 < end) ? csc[e + 1] : sa;
        unsigned o = (((unsigned)(g ? sb : sa)) << 8) | loff;
        uint2 v = ld8(hb, o);
        if (g && (e + 1 >= end)) { v.x = 0u; v.y = 0u; }
        acc8(acc, v);
    }
    acc.x += __shfl_xor(acc.x, 32);
    acc.y += __shfl_xor(acc.y, 32);
    acc.z += __shfl_xor(acc.z, 32);
    acc.w += __shfl_xor(acc.w, 32);
    uint2 vs = ld8(hb, (((unsigned)node) << 8) | loff);  // self loop
    acc8(acc, vs);
    float di = dinv[node];
    float4 bb = reinterpret_cast<const float4*>(bias)[li];
    float ox = fmaxf(fmaf(acc.x, di, bb.x), 0.f);
    float oy = fmaxf(fmaf(acc.y, di, bb.y), 0.f);
    float oz = fmaxf(fmaf(acc.z, di, bb.z), 0.f);
    float ow = fmaxf(fmaf(acc.w, di, bb.w), 0.f);
    if (g == 0)
        reinterpret_cast<uint2*>(out)[(size_t)node * 32 + li] =
            make_uint2(pack_half2(ox, oy), pack_half2(oz, ow));
}

__global__ __launch_bounds__(256) void k_agg2(const __half* __restrict__ h,
                                              const int* __restrict__ offs,
                                              const int* __restrict__ csc,
                                              const float* __restrict__ dinv,
                                              const float* __restrict__ bias,
                                              float* __restrict__ out, int n) {
    int node = (blockIdx.x * 256 + threadIdx.x) >> 6;
    if (node >= n) return;
    int lane = threadIdx.x & 63;
    int g = lane >> 5, li = lane & 31;            // li covers cols 2li..2li+1
    const char* hb = reinterpret_cast<const char*>(h);  // row = 128 B
    const unsigned loff = (unsigned)li << 2;
    int start = __builtin_amdgcn_readfirstlane(offs[node]);
    int end   = __builtin_amdgcn_readfirstlane(offs[node + 1]);
    float2 acc = make_float2(0.f, 0.f);

    int e = start;
    int emain = start + ((end - start) & ~7);
    for (; e < emain; e += 8) {
        int a0 = csc[e],     a1 = csc[e + 1], a2 = csc[e + 2], a3 = csc[e + 3];
        int a4 = csc[e + 4], a5 = csc[e + 5], a6 = csc[e + 6], a7 = csc[e + 7];
        unsigned o0 = (((unsigned)(g ? a1 : a0)) << 7) | loff;
        unsigned o1 = (((unsigned)(g ? a3 : a2)) << 7) | loff;
        unsigned o2 = (((unsigned)(g ? a5 : a4)) << 7) | loff;
        unsigned o3 = (((unsigned)(g ? a7 : a6)) << 7) | loff;
        unsigned v0 = ld4(hb, o0);
        unsigned v1 = ld4(hb, o1);
        unsigned v2 = ld4(hb, o2);
        unsigned v3 = ld4(hb, o3);
        acc4(acc, v0); acc4(acc, v1); acc4(acc, v2); acc4(acc, v3);
    }
    for (; e < end; e += 2) {
        int sa = csc[e];
        int sb = (e + 1 < end) ? csc[e + 1] : sa;
        unsigned o = (((unsigned)(g ? sb : sa)) << 7) | loff;
        unsigned v = ld4(hb, o);
        if (g && (e + 1 >= end)) v = 0u;
        acc4(acc, v);
    }
    acc.x += __shfl_xor(acc.x, 32);
    acc.y += __shfl_xor(acc.y, 32);
    acc4(acc, ld4(hb, (((unsigned)node) << 7) | loff));  // self loop
    float di = dinv[node];
    float2 bb = reinterpret_cast<const float2*>(bias)[li];
    if (g == 0)
        reinterpret_cast<float2*>(out)[(size_t)node * 32 + li] =
            make_float2(fmaf(acc.x, di, bb.x), fmaf(acc.y, di, bb.y));
}

// ---------------------------------------------------------------- launch

extern "C" void kernel_launch(void* const* d_in, const int* in_sizes, int n_in,
                              void* d_out, int out_size, void* d_ws, size_t ws_size,
                              hipStream_t stream) {
    const float* x  = (const float*)d_in[0];
    const int*   ei = (const int*)d_in[1];
    const float* W1 = (const float*)d_in[2];
    const float* b1 = (const float*)d_in[3];
    const float* W2 = (const float*)d_in[4];
    const float* b2 = (const float*)d_in[5];
    float* out = (float*)d_out;

    const int n = in_sizes[0] / 128;   // 100000 (< 2^24: packed pairs valid)
    const int E = in_sizes[1] / 2;     // 1600000
    const int* src = ei;
    const int* dst = ei + E;
    const int NB = (n + 255) / 256;    // 391 buckets of 256 nodes

    // workspace carving (256B aligned)
    char* p = (char*)d_ws;
    auto carve = [&](size_t bytes) -> void* {
        void* r = (void*)p;
        p += (bytes + 255) & ~(size_t)255;
        return r;
    };
    float* dinv    = (float*)carve((size_t)n * 4);
    int*   offs    = (int*)carve((size_t)(n + 1) * 4);
    int*   bcnt    = (int*)carve((size_t)(NB + 1) * 4);
    int*   boffs   = (int*)carve((size_t)(NB + 1) * 4);
    int*   bcur    = (int*)carve((size_t)(NB + 1) * 4);
    __half* Wt1h   = (__half*)carve(16384 * 2);
    __half* Wt2h   = (__half*)carve(8192 * 2);
    int*   csc     = (int*)carve((size_t)E * 4);
    __half* h1     = (__half*)carve((size_t)n * 128 * 2);   // 25.6 MB
    __half* out1   = (__half*)carve((size_t)n * 128 * 2);   // 25.6 MB
    unsigned* pairs = (unsigned*)h1;  // E*4 = 6.4 MB; dead before gemm1
    __half* h2     = h1;              // h1 dead after layer-1 aggregation

    const int gmm  = (n + 63) / 64;       // MFMA gemm blocks (64 rows each)
    const int gagg = (n + 3) / 4;
    const int GB   = 256;                 // bucket-pass blocks
    const int epb  = (E + GB - 1) / GB;   // edges per block

    // ---- init: weight convert+transpose + zero bcnt ----
    k_wconv<<<96, 256, 0, stream>>>(W1, W2, Wt1h, Wt2h, bcnt, NB + 1);

    // ---- CSC build (bucketed counting sort by dst) ----
    k_bhist<<<GB, 256, 0, stream>>>(dst, E, bcnt, NB, epb);
    k_bscan<<<1, 512, 0, stream>>>(bcnt, boffs, bcur, NB, E);
    k_bscatter<<<GB, 256, 0, stream>>>(src, dst, E, bcur, pairs, NB, epb);
    k_bfinal<<<NB, 256, 0, stream>>>(pairs, boffs, dinv, offs, csc, n, E, NB);

    // ---- layer 1: h1 = f16((x @ W1) * dinv) ; out1 = f16(relu(agg*dinv + b1)) ----
    gemm1_mfma<<<gmm, 256, 0, stream>>>(x, Wt1h, dinv, h1, n);
    k_agg1<<<gagg, 256, 0, stream>>>(h1, offs, csc, dinv, b1, out1, n);

    // ---- layer 2: h2 = f16((out1 @ W2) * dinv) ; out = agg*dinv + b2 ----
    gemm2_mfma<<<gmm, 256, 0, stream>>>(out1, Wt2h, dinv, h2, n);
    k_agg2<<<gagg, 256, 0, stream>>>(h2, offs, csc, dinv, b2, out, n);
}